// Round 16
// baseline (228.073 us; speedup 1.0000x reference)
//
#include <hip/hip_runtime.h>
#include <hip/hip_bf16.h>
#include <stdint.h>

// B=4, T=4096, K=256, D=1024, H=16, hd=64
#define D_DIM 1024

using f32x4  = __attribute__((ext_vector_type(4))) float;
using short8 = __attribute__((ext_vector_type(8))) short;

__device__ __forceinline__ float bf2f(unsigned short u) {
    union { unsigned int i; float f; } v; v.i = ((unsigned int)u) << 16; return v.f;
}
__device__ __forceinline__ unsigned short f2bf(float f) {
    union { float f; unsigned int i; } v; v.f = f;
    unsigned int x = v.i;
    return (unsigned short)((x + 0x7fffu + ((x >> 16) & 1u)) >> 16);  // RNE
}
__device__ __forceinline__ void gload16(const void* g, void* l) {
    __builtin_amdgcn_global_load_lds(
        (const __attribute__((address_space(1))) void*)g,
        (__attribute__((address_space(3))) void*)l, 16, 0, 0);
}

// ---------------------------------------------------------------------------
// convw: Wk,Wv -> gamma_kv-folded hi/lo bf16; Wo -> bf16.
// ---------------------------------------------------------------------------
__global__ __launch_bounds__(256)
void convw_kernel(const float* __restrict__ Wk, const float* __restrict__ Wv,
                  const float* __restrict__ Wo, const float* __restrict__ gkv,
                  unsigned short* __restrict__ wk_hi, unsigned short* __restrict__ wk_lo,
                  unsigned short* __restrict__ wv_hi, unsigned short* __restrict__ wv_lo,
                  unsigned short* __restrict__ wo_b)
{
    const int e   = (blockIdx.x * 256 + threadIdx.x) * 4;
    const int sel = e >> 20;
    const int off = e & 0xFFFFF;
    const float* src = sel == 0 ? Wk : sel == 1 ? Wv : Wo;
    float4 v = *(const float4*)(src + off);
    if (sel < 2) {
        float4 g = *(const float4*)(gkv + (off & 1023));
        v.x *= g.x; v.y *= g.y; v.z *= g.z; v.w *= g.w;
        ushort4 h, l;
        h.x = f2bf(v.x); l.x = f2bf(v.x - bf2f(h.x));
        h.y = f2bf(v.y); l.y = f2bf(v.y - bf2f(h.y));
        h.z = f2bf(v.z); l.z = f2bf(v.z - bf2f(h.z));
        h.w = f2bf(v.w); l.w = f2bf(v.w - bf2f(h.w));
        unsigned short* hi = sel == 0 ? wk_hi : wv_hi;
        unsigned short* lo = sel == 0 ? wk_lo : wv_lo;
        *(ushort4*)(hi + off) = h;
        *(ushort4*)(lo + off) = l;
    } else {
        ushort4 o;
        o.x = f2bf(v.x); o.y = f2bf(v.y); o.z = f2bf(v.z); o.w = f2bf(v.w);
        *(ushort4*)(wo_b + off) = o;
    }
}

// ---------------------------------------------------------------------------
// transq: wqT[i][c] = gamma_q[i] * Wq[c][i], split hi/lo bf16.
// ---------------------------------------------------------------------------
__global__ __launch_bounds__(256)
void transq_kernel(const float* __restrict__ Wq, const float* __restrict__ gq,
                   unsigned short* __restrict__ th, unsigned short* __restrict__ tl)
{
    __shared__ float tile[64][65];
    const int c0 = (blockIdx.x & 15) * 64;
    const int i0 = (blockIdx.x >> 4) * 64;
    const int tid = threadIdx.x;
#pragma unroll
    for (int j = 0; j < 4; ++j) {
        const int e  = tid + j * 256;
        const int rl = e >> 4;
        const int q4 = e & 15;
        float4 v = *(const float4*)(Wq + (long)(c0 + rl) * 1024 + i0 + q4 * 4);
        tile[q4 * 4 + 0][rl] = v.x;
        tile[q4 * 4 + 1][rl] = v.y;
        tile[q4 * 4 + 2][rl] = v.z;
        tile[q4 * 4 + 3][rl] = v.w;
    }
    __syncthreads();
#pragma unroll
    for (int j = 0; j < 4; ++j) {
        const int e  = tid + j * 256;
        const int il = e >> 4;
        const int s4 = e & 15;
        const float g = gq[i0 + il];
        float v0 = tile[il][s4 * 4 + 0] * g;
        float v1 = tile[il][s4 * 4 + 1] * g;
        float v2 = tile[il][s4 * 4 + 2] * g;
        float v3 = tile[il][s4 * 4 + 3] * g;
        ushort4 hh, ll;
        hh.x = f2bf(v0); ll.x = f2bf(v0 - bf2f(hh.x));
        hh.y = f2bf(v1); ll.y = f2bf(v1 - bf2f(hh.y));
        hh.z = f2bf(v2); ll.z = f2bf(v2 - bf2f(hh.z));
        hh.w = f2bf(v3); ll.w = f2bf(v3 - bf2f(hh.w));
        const long o = (long)(i0 + il) * 1024 + c0 + s4 * 4;
        *(ushort4*)(th + o) = hh;
        *(ushort4*)(tl + o) = ll;
    }
}

// ---------------------------------------------------------------------------
// RMSNorm + split for ctx rows.
// ---------------------------------------------------------------------------
__global__ __launch_bounds__(256)
void rms_split_kernel(const float* __restrict__ x,
                      unsigned short* __restrict__ xh, unsigned short* __restrict__ xl)
{
    const long row = blockIdx.x;
    float4 v = ((const float4*)(x + row * D_DIM))[threadIdx.x];
    float ss = v.x*v.x + v.y*v.y + v.z*v.z + v.w*v.w;
#pragma unroll
    for (int m = 32; m; m >>= 1) ss += __shfl_xor(ss, m);
    __shared__ float red[4];
    if ((threadIdx.x & 63) == 0) red[threadIdx.x >> 6] = ss;
    __syncthreads();
    const float tot = red[0] + red[1] + red[2] + red[3];
    const float scale = rsqrtf(tot * (1.0f / 1024.0f) + 1.1920929e-07f);
    v.x *= scale; v.y *= scale; v.z *= scale; v.w *= scale;
    ushort4 h, l;
    h.x = f2bf(v.x); l.x = f2bf(v.x - bf2f(h.x));
    h.y = f2bf(v.y); l.y = f2bf(v.y - bf2f(h.y));
    h.z = f2bf(v.z); l.z = f2bf(v.z - bf2f(h.z));
    h.w = f2bf(v.w); l.w = f2bf(v.w - bf2f(h.w));
    *(ushort4*)(xh + row * D_DIM + threadIdx.x * 4) = h;
    *(ushort4*)(xl + row * D_DIM + threadIdx.x * 4) = l;
}

// ---------------------------------------------------------------------------
// gemm_kv: z=0: k split-precision -> kh/kl bf16. z=1: v ~= ch@Wv'_hi^T -> f32.
// ---------------------------------------------------------------------------
__global__ __launch_bounds__(256)
void gemm_kv(const unsigned short* __restrict__ ch, const unsigned short* __restrict__ cl,
             const unsigned short* __restrict__ wkh, const unsigned short* __restrict__ wkl,
             const unsigned short* __restrict__ wvh,
             unsigned short* __restrict__ kh, unsigned short* __restrict__ kl,
             float* __restrict__ v_f)
{
    __shared__ unsigned short Ah[4096], Al[4096], Bh[4096], Bl[4096];
    const bool full = (blockIdx.z == 0);
    const unsigned short* Bhp = full ? wkh : wvh;
    const unsigned short* Blp = wkl;

    const int tid = threadIdx.x, lane = tid & 63, wave = tid >> 6;
    const int wm = wave >> 1, wn = wave & 1;
    const long Arow0 = (long)blockIdx.y * 128;
    const int  Brow0 = blockIdx.x * 128;
    const int fr = lane & 15, ks = lane >> 4;
    const int ksz = (ks ^ ((fr >> 1) & 3)) << 4;
    const int kq  = ((tid & 3) ^ ((tid >> 3) & 3)) * 8;
    const int srow = tid >> 2;

    const long a_off0 = (Arow0 + srow) * D_DIM + kq;
    const long a_off1 = (Arow0 + srow + 64) * D_DIM + kq;
    const long b_off0 = (long)(Brow0 + srow) * D_DIM + kq;
    const long b_off1 = (long)(Brow0 + srow + 64) * D_DIM + kq;

    f32x4 acc[4][4] = {};
    char* AhB = (char*)Ah; char* AlB = (char*)Al;
    char* BhB = (char*)Bh; char* BlB = (char*)Bl;

    for (int kt = 0; kt < 32; ++kt) {
        const int k0 = kt * 32;
        gload16(ch + a_off0 + k0, AhB + tid * 16);
        gload16(ch + a_off1 + k0, AhB + 4096 + tid * 16);
        gload16(Bhp + b_off0 + k0, BhB + tid * 16);
        gload16(Bhp + b_off1 + k0, BhB + 4096 + tid * 16);
        if (full) {
            gload16(cl + a_off0 + k0, AlB + tid * 16);
            gload16(cl + a_off1 + k0, AlB + 4096 + tid * 16);
            gload16(Blp + b_off0 + k0, BlB + tid * 16);
            gload16(Blp + b_off1 + k0, BlB + 4096 + tid * 16);
        }
        __syncthreads();

        short8 ah[4], al[4], bh[4], bl[4];
#pragma unroll
        for (int mi = 0; mi < 4; ++mi) {
            const int aoff = (wm * 64 + mi * 16 + fr) * 64 + ksz;
            ah[mi] = *(const short8*)(AhB + aoff);
            if (full) al[mi] = *(const short8*)(AlB + aoff);
        }
#pragma unroll
        for (int ni = 0; ni < 4; ++ni) {
            const int boff = (wn * 64 + ni * 16 + fr) * 64 + ksz;
            bh[ni] = *(const short8*)(BhB + boff);
            if (full) bl[ni] = *(const short8*)(BlB + boff);
        }
#pragma unroll
        for (int mi = 0; mi < 4; ++mi)
#pragma unroll
            for (int ni = 0; ni < 4; ++ni) {
                acc[mi][ni] = __builtin_amdgcn_mfma_f32_16x16x32_bf16(ah[mi], bh[ni], acc[mi][ni], 0, 0, 0);
                if (full) {
                    acc[mi][ni] = __builtin_amdgcn_mfma_f32_16x16x32_bf16(al[mi], bh[ni], acc[mi][ni], 0, 0, 0);
                    acc[mi][ni] = __builtin_amdgcn_mfma_f32_16x16x32_bf16(ah[mi], bl[ni], acc[mi][ni], 0, 0, 0);
                }
            }
        __syncthreads();
    }

    const int c = lane & 15, r0 = (lane >> 4) * 4;
#pragma unroll
    for (int mi = 0; mi < 4; ++mi)
#pragma unroll
        for (int ni = 0; ni < 4; ++ni)
#pragma unroll
            for (int j = 0; j < 4; ++j) {
                const long row = Arow0 + wm * 64 + mi * 16 + r0 + j;
                const int  col = Brow0 + wn * 64 + ni * 16 + c;
                const float val = acc[mi][ni][j];
                if (full) {
                    const unsigned short hh = f2bf(val);
                    kh[row * D_DIM + col] = hh;
                    kl[row * D_DIM + col] = f2bf(val - bf2f(hh));
                } else {
                    v_f[row * D_DIM + col] = val;
                }
            }
}

// ---------------------------------------------------------------------------
// gemm_U: U[b,p,h][i] = sum_d (kh+kl)[(b,p),h*64+d]*(wqT_h+l)[i,h*64+d],
// epilogue -> bf16 hi/lo (Uh/Ul).
// ---------------------------------------------------------------------------
__global__ __launch_bounds__(256)
void gemm_U(const unsigned short* __restrict__ kh, const unsigned short* __restrict__ kl,
            const unsigned short* __restrict__ th, const unsigned short* __restrict__ tl,
            unsigned short* __restrict__ Uh, unsigned short* __restrict__ Ul)
{
    __shared__ unsigned short Ah[4096], Al[4096], Bh[4096], Bl[4096];
    const int h = blockIdx.z;
    const int tid = threadIdx.x, lane = tid & 63, wave = tid >> 6;
    const int wm = wave >> 1, wn = wave & 1;
    const long Arow0 = (long)blockIdx.y * 128;
    const int  Brow0 = blockIdx.x * 128;
    const int fr = lane & 15, ks = lane >> 4;
    const int ksz = (ks ^ ((fr >> 1) & 3)) << 4;
    const int kq  = ((tid & 3) ^ ((tid >> 3) & 3)) * 8;
    const int srow = tid >> 2;
    const int kb = h * 64;

    const long a_off0 = (Arow0 + srow) * D_DIM + kb + kq;
    const long a_off1 = (Arow0 + srow + 64) * D_DIM + kb + kq;
    const long b_off0 = (long)(Brow0 + srow) * D_DIM + kb + kq;
    const long b_off1 = (long)(Brow0 + srow + 64) * D_DIM + kb + kq;

    f32x4 acc[4][4] = {};
    char* AhB = (char*)Ah; char* AlB = (char*)Al;
    char* BhB = (char*)Bh; char* BlB = (char*)Bl;

    for (int kt = 0; kt < 2; ++kt) {
        const int k0 = kt * 32;
        gload16(kh + a_off0 + k0, AhB + tid * 16);
        gload16(kh + a_off1 + k0, AhB + 4096 + tid * 16);
        gload16(kl + a_off0 + k0, AlB + tid * 16);
        gload16(kl + a_off1 + k0, AlB + 4096 + tid * 16);
        gload16(th + b_off0 + k0, BhB + tid * 16);
        gload16(th + b_off1 + k0, BhB + 4096 + tid * 16);
        gload16(tl + b_off0 + k0, BlB + tid * 16);
        gload16(tl + b_off1 + k0, BlB + 4096 + tid * 16);
        __syncthreads();

        short8 ah[4], al[4], bh[4], bl[4];
#pragma unroll
        for (int mi = 0; mi < 4; ++mi) {
            const int aoff = (wm * 64 + mi * 16 + fr) * 64 + ksz;
            ah[mi] = *(const short8*)(AhB + aoff);
            al[mi] = *(const short8*)(AlB + aoff);
        }
#pragma unroll
        for (int ni = 0; ni < 4; ++ni) {
            const int boff = (wn * 64 + ni * 16 + fr) * 64 + ksz;
            bh[ni] = *(const short8*)(BhB + boff);
            bl[ni] = *(const short8*)(BlB + boff);
        }
#pragma unroll
        for (int mi = 0; mi < 4; ++mi)
#pragma unroll
            for (int ni = 0; ni < 4; ++ni) {
                acc[mi][ni] = __builtin_amdgcn_mfma_f32_16x16x32_bf16(ah[mi], bh[ni], acc[mi][ni], 0, 0, 0);
                acc[mi][ni] = __builtin_amdgcn_mfma_f32_16x16x32_bf16(al[mi], bh[ni], acc[mi][ni], 0, 0, 0);
                acc[mi][ni] = __builtin_amdgcn_mfma_f32_16x16x32_bf16(ah[mi], bl[ni], acc[mi][ni], 0, 0, 0);
            }
        __syncthreads();
    }

    const int c = lane & 15, r0 = (lane >> 4) * 4;
#pragma unroll
    for (int mi = 0; mi < 4; ++mi)
#pragma unroll
        for (int ni = 0; ni < 4; ++ni)
#pragma unroll
            for (int j = 0; j < 4; ++j) {
                const long row = Arow0 + wm * 64 + mi * 16 + r0 + j;
                const int  col = Brow0 + wn * 64 + ni * 16 + c;
                const float val = acc[mi][ni][j];
                const long o = ((long)row * 16 + h) * 1024 + col;
                const unsigned short hh = f2bf(val);
                Uh[o] = hh;
                Ul[o] = f2bf(val - bf2f(hh));
            }
}

// ---------------------------------------------------------------------------
// score v5: deep-pipelined p-group GEMM with K-SPLIT. x prefetched 2 tiles
// ahead (alternating named reg pairs, no copies); U staged 3 tiles ahead into
// 4 LDS regions (manual vmcnt(6) mid-iter guarantees U(t+1) before barrier;
// compiler's register-dep waits cover x). Raw s_barrier + lgkmcnt(0) +
// sched_barrier(0) pins (r14/r15 discipline). Tail iters (t>=12) drain.
// ---------------------------------------------------------------------------
__global__ __launch_bounds__(256)
void score_gemm(const float* __restrict__ x, const int* __restrict__ cidx,
                const unsigned short* __restrict__ Uh, const unsigned short* __restrict__ Ul,
                float* __restrict__ sbuf, float* __restrict__ ssbuf)
{
    const int pg = blockIdx.x;
    const int mh = blockIdx.y;
    const int bz = blockIdx.z;
    const int b  = bz & 3;
    const int ksp = bz >> 2;
    const int kbase = ksp << 9;
    const int p0 = pg * 4;
    const int* ci = cidx + (b << 12);
    int l = 0, r = 4096;
    while (l < r) { int m = (l + r) >> 1; if (ci[m] < p0 - 1) l = m + 1; else r = m; }
    const int lo = l;
    r = 4096;
    while (l < r) { int m = (l + r) >> 1; if (ci[m] <= p0 + 4) l = m + 1; else r = m; }
    const int hi = l;
    if (lo + mh * 64 >= hi) return;

    float* const sb = sbuf + (long)ksp * 786432;
    float* const ssb = ssbuf + (ksp << 14);

    __shared__ unsigned short AhS[2][2048], AlS[2][2048];   // 2 regions x 4KB
    __shared__ unsigned short UhS[4][2048], UlS[4][2048];   // 4 regions x 4KB

    const int tid = threadIdx.x, lane = tid & 63, wave = tid >> 6;
    const int fr = lane & 15;
    const int ks = lane >> 4;
    const int ksz = (ks ^ ((fr >> 1) & 3)) << 4;

    const int arow = tid >> 2, aq = tid & 3;
    const int aslot = aq ^ ((arow >> 1) & 3);
    const unsigned short* const Uhb = Uh + ((long)((b << 8) + p0) * 16) * 1024 + kbase;
    const unsigned short* const Ulb = Ul + ((long)((b << 8) + p0) * 16) * 1024 + kbase;
    const float* const xb = x + ((long)b << 12) * 1024 + kbase;

#define USTAGE(T) do {                                                        \
    const int kofs_ = (T) * 32;                                               \
    gload16(Uhb + (long)arow * 1024 + kofs_ + aslot * 8,                      \
            (char*)&UhS[(T) & 3][0] + tid * 16);                              \
    gload16(Ulb + (long)arow * 1024 + kofs_ + aslot * 8,                      \
            (char*)&UlS[(T) & 3][0] + tid * 16); } while (0)

#define SPLITW(RG, V0, V1) do {                                               \
    ss += V0.x*V0.x + V0.y*V0.y + V0.z*V0.z + V0.w*V0.w                       \
        + V1.x*V1.x + V1.y*V1.y + V1.z*V1.z + V1.w*V1.w;                      \
    short8 hv, lv; unsigned short h_;                                         \
    h_ = f2bf(V0.x); hv[0] = (short)h_; lv[0] = (short)f2bf(V0.x - bf2f(h_)); \
    h_ = f2bf(V0.y); hv[1] = (short)h_; lv[1] = (short)f2bf(V0.y - bf2f(h_)); \
    h_ = f2bf(V0.z); hv[2] = (short)h_; lv[2] = (short)f2bf(V0.z - bf2f(h_)); \
    h_ = f2bf(V0.w); hv[3] = (short)h_; lv[3] = (short)f2bf(V0.w - bf2f(h_)); \
    h_ = f2bf(V1.x); hv[4] = (short)h_; lv[4] = (short)f2bf(V1.x - bf2f(h_)); \
    h_ = f2bf(V1.y); hv[5] = (short)h_; lv[5] = (short)f2bf(V1.y - bf2f(h_)); \
    h_ = f2bf(V1.z); hv[6] = (short)h_; lv[6] = (short)f2bf(V1.z - bf2f(h_)); \
    h_ = f2bf(V1.w); hv[7] = (short)h_; lv[7] = (short)f2bf(V1.w - bf2f(h_)); \
    *(short8*)((char*)&AhS[RG][0] + arow * 64 + aslot * 16) = hv;             \
    *(short8*)((char*)&AlS[RG][0] + arow * 64 + aslot * 16) = lv; } while (0)

    // ITER(T): consume XC (=x(T+1)) into region (T+1)&1, load XN (=x(T+2)).
#define ITER(T, XC0, XC1, XN0, XN1) do {                                      \
    if ((T) + 2 <= 15) {                                                      \
        const float* xp_ = xr + ((T) + 2) * 32;                               \
        XN0 = *(const float4*)(xp_); XN1 = *(const float4*)(xp_ + 4);         \
    }                                                                         \
    if ((T) + 3 <= 15) USTAGE((T) + 3);                                       \
    {                                                                         \
        const int aoff_ = (((T) & 1)) * 4096 + (wave * 16 + fr) * 64 + ksz;   \
        const short8 ah_ = *(const short8*)((char*)&AhS[0][0] + aoff_);       \
        const short8 al_ = *(const short8*)((char*)&AlS[0][0] + aoff_);       \
        __builtin_amdgcn_s_setprio(1);                                        \
        _Pragma("unroll")                                                     \
        for (int ni = 0; ni < 4; ++ni) {                                      \
            const int boff_ = (((T) & 3)) * 4096 + (ni * 16 + fr) * 64 + ksz; \
            const short8 uh_ = *(const short8*)((char*)&UhS[0][0] + boff_);   \
            const short8 ul_ = *(const short8*)((char*)&UlS[0][0] + boff_);   \
            acc[ni] = __builtin_amdgcn_mfma_f32_16x16x32_bf16(ah_, uh_, acc[ni], 0, 0, 0); \
            acc[ni] = __builtin_amdgcn_mfma_f32_16x16x32_bf16(al_, uh_, acc[ni], 0, 0, 0); \
            acc[ni] = __builtin_amdgcn_mfma_f32_16x16x32_bf16(ah_, ul_, acc[ni], 0, 0, 0); \
        }                                                                     \
        __builtin_amdgcn_s_setprio(0);                                        \
    }                                                                         \
    if ((T) >= 12) asm volatile("s_waitcnt vmcnt(0)" ::: "memory");           \
    else           asm volatile("s_waitcnt vmcnt(6)" ::: "memory");           \
    __builtin_amdgcn_sched_barrier(0);                                        \
    if ((T) + 1 <= 15) SPLITW(((T) + 1) & 1, XC0, XC1);                       \
    asm volatile("s_waitcnt lgkmcnt(0)" ::: "memory");                        \
    __builtin_amdgcn_sched_barrier(0);                                        \
    __builtin_amdgcn_s_barrier();                                             \
    __builtin_amdgcn_sched_barrier(0); } while (0)

    for (int t0 = lo + mh * 64; t0 < hi; t0 += 128) {
        const int tc0 = (t0 + arow < hi) ? (t0 + arow) : (hi - 1);
        const float* xr = xb + (long)tc0 * 1024 + aq * 8;
        float ss = 0.f;

        float4 xa0, xa1, xb0, xb1;
        // prologue FIFO order: [x0, U0, U1, x1, U2]
        xa0 = *(const float4*)(xr); xa1 = *(const float4*)(xr + 4);
        USTAGE(0); USTAGE(1);
        xb0 = *(const float4*)(xr + 32); xb1 = *(const float4*)(xr + 36);
        USTAGE(2);
        SPLITW(0, xa0, xa1);                       // compiler waits x0
        asm volatile("s_waitcnt vmcnt(4)" ::: "memory");   // U0,U1 landed
        asm volatile("s_waitcnt lgkmcnt(0)" ::: "memory");
        __builtin_amdgcn_sched_barrier(0);
        __builtin_amdgcn_s_barrier();
        __builtin_amdgcn_sched_barrier(0);

        f32x4 acc[4] = {};
#pragma unroll
        for (int tt = 0; tt < 16; tt += 2) {
            ITER(tt,     xb0, xb1, xa0, xa1);
            ITER(tt + 1, xa0, xa1, xb0, xb1);
        }

        // ---- partial sum(x^2) over this K-half -> ssbuf ----
        ss += __shfl_xor(ss, 1);
        ss += __shfl_xor(ss, 2);
        if (aq == 0 && t0 + arow < hi)
            ssb[(b << 12) + t0 + arow] = ss;

        // ---- epilogue: scatter raw partial dots ----
        const int hcol = lane & 15;
        const int r0j = (lane >> 4) * 4;
#pragma unroll
        for (int j = 0; j < 4; ++j) {
            const int trow = t0 + wave * 16 + r0j + j;
            if (trow < hi) {
                const long tg = ((long)b << 12) + trow;
                const int idx = ci[trow];
#pragma unroll
                for (int ni = 0; ni < 4; ++ni) {
                    const int dp = p0 + ni - idx + 1;
                    if (dp >= 0 && dp <= 2)
                        sb[(tg * 16 + hcol) * 3 + dp] = acc[ni][j];
                }
            }
        }
        __syncthreads();   // LDS reuse safety before next tile's prologue
    }
#undef USTAGE
#undef SPLITW
#undef ITER
}

// ---------------------------------------------------------------------------
// attnout: dot = sum of K-halves; s = dot*rsqrt(mean xx+eps)/8; w=relu(s)^2,
// normalize, out = sum w*v. ao bf16.
// ---------------------------------------------------------------------------
__global__ __launch_bounds__(256)
void attnout_kernel(const float* __restrict__ sbuf, const float* __restrict__ ssbuf,
                    const float* __restrict__ vf, const int* __restrict__ cidx,
                    unsigned short* __restrict__ ao)
{
    const int tid = threadIdx.x;
    const int tg = tid >> 4, h = tid & 15;
    const int t = blockIdx.x * 16 + tg;
    const int b = t >> 12;
    const int idx = cidx[t];
    const float* sb0 = sbuf + ((long)t * 16 + h) * 3;
    const float* sb1 = sb0 + 786432;
    const float ssum = ssbuf[t] + ssbuf[t + 16384];
    const float scale = rsqrtf(ssum * (1.0f / 1024.0f) + 1.1920929e-07f) * 0.125f;
    float w0 = 0.f, w1 = 0.f, w2 = 0.f, wsum = 0.f;
    if (idx - 1 >= 0) { float s = (sb0[0] + sb1[0]) * scale; if (s > 0.f) { w0 = s * s; wsum += w0; } }
    { float s = (sb0[1] + sb1[1]) * scale; if (s > 0.f) { w1 = s * s; wsum += w1; } }
    if (idx + 1 < 256) { float s = (sb0[2] + sb1[2]) * scale; if (s > 0.f) { w2 = s * s; wsum += w2; } }
    const float inv = 1.0f / fmaxf(wsum, 1e-6f);
    w0 *= inv; w1 *= inv; w2 *= inv;
    const int p0 = idx > 0 ? idx - 1 : 0;
    const int p2 = idx < 255 ? idx + 1 : 255;
    const float4* v0 = (const float4*)(vf + ((long)(b * 256 + p0)) * 1024 + h * 64);
    const float4* v1 = (const float4*)(vf + ((long)(b * 256 + idx)) * 1024 + h * 64);
    const float4* v2 = (const float4*)(vf + ((long)(b * 256 + p2)) * 1024 + h * 64);
    ushort4* aop = (ushort4*)(ao + (long)t * 1024 + h * 64);
#pragma unroll
    for (int q = 0; q < 16; ++q) {
        float4 a0 = v0[q], a1 = v1[q], a2 = v2[q];
        ushort4 o;
        o.x = f2bf(w0 * a0.x + w1 * a1.x + w2 * a2.x);
        o.y = f2bf(w0 * a0.y + w1 * a1.y + w2 * a2.y);
        o.z = f2bf(w0 * a0.z + w1 * a1.z + w2 * a2.z);
        o.w = f2bf(w0 * a0.w + w1 * a1.w + w2 * a2.w);
        aop[q] = o;
    }
}

// ---------------------------------------------------------------------------
// out = x + ao @ Wo^T, 256x256, swizzled, 8-PHASE deep-pipelined (r15, win).
// ---------------------------------------------------------------------------
__global__ __launch_bounds__(512, 2)
void gemm_out256(const unsigned short* __restrict__ A,
                 const unsigned short* __restrict__ W,
                 float* __restrict__ C, const float* __restrict__ resid)
{
    __shared__ unsigned short As[4][8192];
    __shared__ unsigned short Bs[4][8192];

    const int lin = blockIdx.x;
    const int bx = (lin >> 3) & 3;
    const int by = ((lin >> 5) << 3) | (lin & 7);
    const long row0 = (long)by * 256;
    const int  col0 = bx * 256;

    const int tid = threadIdx.x, lane = tid & 63, wave = tid >> 6;
    const int wm = wave >> 2, wn = wave & 3;
    const int fr = lane & 15, ks = lane >> 4;
    const int ksz = (ks ^ ((fr >> 1) & 3)) << 4;
    const int kq  = ((tid & 3) ^ ((tid >> 3) & 3)) * 8;
    const int srow = tid >> 2;

    const long a_off0 = (row0 + srow) * D_DIM + kq;
    const long a_off1 = (row0 + 128 + srow) * D_DIM + kq;
    const long b_off0 = (long)(col0 + srow) * D_DIM + kq;
    const long b_off1 = (long)(col0 + 128 + srow) * D_DIM + kq;

    f32x4 acc[8][4] = {};

#define STAGE_A(X) do { const int kofs_ = (X) * 32;                          \
    char* base_ = (char*)&As[(X) & 3][0];                                    \
    gload16(A + a_off0 + kofs_, base_ + tid * 16);                           \
    gload16(A + a_off1 + kofs_, base_ + 8192 + tid * 16); } while (0)
#define STAGE_B(X) do { const int kofs_ = (X) * 32;                          \
    char* base_ = (char*)&Bs[(X) & 3][0];                                    \
    gload16(W + b_off0 + kofs_, base_ + tid * 16);                           \
    gload16(W + b_off1 + kofs_, base_ + 8192 + tid * 16); } while (0)

    STAGE_A(0); STAGE_B(0); STAGE_A(1); STAGE_B(1); STAGE_A(2); STAGE_B(2);
    asm volatile("s_waitcnt vmcnt(4)" ::: "memory");
    __builtin_amdgcn_s_barrier();
    __builtin_amdgcn_sched_barrier(0);

    short8 bfrag[4];

    for (int i = 0; i < 8; ++i) {
        const int Tb = i * 4;
        const bool last = (i == 7);
#pragma unroll
        for (int ph = 0; ph < 8; ++ph) {
            const int tp = ph >> 1;
            const int h  = ph & 1;
            const int rg = tp;
            if (h == 0) {
#pragma unroll
                for (int ni = 0; ni < 4; ++ni)
                    bfrag[ni] = *(const short8*)((char*)&Bs[rg][0] +
                                (wn * 64 + ni * 16 + fr) * 64 + ksz);
            }
            short8 afrag[4];
#pragma unroll
            for (int mi = 0; mi < 4; ++mi)
                afrag[mi] = *(const short8*)((char*)&As[rg][0] +
                            (wm * 128 + h * 64 + mi * 16 + fr) * 64 + ksz);
            {
                const int SX = Tb + 3 + tp;
                if (SX < 32) {
                    if (h == 0) STAGE_A(SX); else STAGE_B(SX);
                }
            }
            if (ph == 3) {
                if (last) asm volatile("s_waitcnt vmcnt(0)" ::: "memory");
                else      asm volatile("s_waitcnt vmcnt(4)" ::: "memory");
            } else if (ph == 7) {
                if (!last) asm volatile("s_waitcnt vmcnt(4)" ::: "memory");
            }
            __builtin_amdgcn_s_barrier();
            asm volatile("s_waitcnt lgkmcnt(0)" ::: "memory");
            __builtin_amdgcn_sched_barrier(0);
            __builtin_amdgcn_s_setprio(1);
#pragma unroll
            for (int mi = 0; mi < 4; ++mi)
#pragma unroll
                for (int ni = 0; ni < 4; ++ni)
                    acc[h * 4 + mi][ni] = __builtin_amdgcn_mfma_f32_16x16x32_bf16(
                        afrag[mi], bfrag[ni], acc[h * 4 + mi][ni], 0, 0, 0);
            __builtin_amdgcn_s_setprio(0);
            __builtin_amdgcn_sched_barrier(0);
            __builtin_amdgcn_s_barrier();
            __builtin_amdgcn_sched_barrier(0);
        }
    }
#undef STAGE_A
#undef STAGE_B

    const int c = lane & 15, rg2 = lane >> 4;
#pragma unroll
    for (int mi = 0; mi < 8; ++mi)
#pragma unroll
        for (int ni = 0; ni < 4; ++ni)
#pragma unroll
            for (int j = 0; j < 4; ++j) {
                const long row = row0 + wm * 128 + mi * 16 + rg2 * 4 + j;
                const int  col = col0 + wn * 64 + ni * 16 + c;
                C[row * D_DIM + col] = resid[row * D_DIM + col] + acc[mi][ni][j];
            }
}

// ---------------------------------------------------------------------------
extern "C" void kernel_launch(void* const* d_in, const int* in_sizes, int n_in,
                              void* d_out, int out_size, void* d_ws, size_t ws_size,
                              hipStream_t stream)
{
    const float* x    = (const float*)d_in[0];
    const float* ctx  = (const float*)d_in[1];
    const int*   cidx = (const int*)d_in[2];
    const float* gq   = (const float*)d_in[3];
    const float* gkv  = (const float*)d_in[4];
    const float* Wq   = (const float*)d_in[5];
    const float* Wk   = (const float*)d_in[6];
    const float* Wv   = (const float*)d_in[7];
    const float* Wo   = (const float*)d_in[8];
    float* out = (float*)d_out;

    char* ws = (char*)d_ws;
    const size_t MB = 1 << 20;
    unsigned short* wqT_hi = (unsigned short*)(ws + 0 * MB);
    unsigned short* wqT_lo = (unsigned short*)(ws + 2 * MB);
    unsigned short* wk_hi  = (unsigned short*)(ws + 4 * MB);
    unsigned short* wk_lo  = (unsigned short*)(ws + 6 * MB);
    unsigned short* wv_hi  = (unsigned short*)(ws + 8 * MB);
    unsigned short* wv_lo  = (unsigned short*)(ws + 10 * MB);
    unsigned short* wo_b   = (unsigned short*)(ws + 12 * MB);
    unsigned short* ch = (unsigned short*)(ws + 14 * MB);
    unsigned short* cl = (unsigned short*)(ws + 16 * MB);
    unsigned short* kh = (unsigned short*)(ws + 18 * MB);
    unsigned short* kl = (unsigned short*)(ws + 20 * MB);
    float* v_f = (float*)(ws + 22 * MB);                      // 4MB
    unsigned short* Uh = (unsigned short*)(ws + 26 * MB);     // 32MB (26..58)
    unsigned short* Ul = (unsigned short*)(ws + 58 * MB);     // 32MB (58..90)
    unsigned short* ao_b = (unsigned short*)(ws + 26 * MB);   // 32MB, ALIASES Uh
        // (Uh dead after score_gemm; attnout writes ao afterwards)
    float* sbuf  = (float*)(ws + 91 * MB);                    // 2 x 3MB (91..97)
    float* ssbuf = (float*)(ws + 97 * MB);                    // 2 x 64KB; total ~98MB

    convw_kernel<<<3072, 256, 0, stream>>>(Wk, Wv, Wo, gkv,
                                           wk_hi, wk_lo, wv_hi, wv_lo, wo_b);
    transq_kernel<<<256, 256, 0, stream>>>(Wq, gq, wqT_hi, wqT_lo);
    rms_split_kernel<<<1024, 256, 0, stream>>>(ctx, ch, cl);
    gemm_kv<<<dim3(8, 8, 2), 256, 0, stream>>>(ch, cl, wk_hi, wk_lo, wv_hi,
                                               kh, kl, v_f);
    gemm_U<<<dim3(8, 8, 16), 256, 0, stream>>>(kh, kl, wqT_hi, wqT_lo, Uh, Ul);
    score_gemm<<<dim3(64, 2, 8), 256, 0, stream>>>(x, cidx, Uh, Ul, sbuf, ssbuf);
    attnout_kernel<<<1024, 256, 0, stream>>>(sbuf, ssbuf, v_f, cidx, ao_b);
    gemm_out256<<<256, 512, 0, stream>>>(ao_b, wo_b, out, x);
}

// Round 17
// 198.555 us; speedup vs baseline: 1.1487x; 1.1487x over previous
//
#include <hip/hip_runtime.h>
#include <hip/hip_bf16.h>
#include <stdint.h>

// B=4, T=4096, K=256, D=1024, H=16, hd=64
#define D_DIM 1024

using f32x4  = __attribute__((ext_vector_type(4))) float;
using short8 = __attribute__((ext_vector_type(8))) short;

__device__ __forceinline__ float bf2f(unsigned short u) {
    union { unsigned int i; float f; } v; v.i = ((unsigned int)u) << 16; return v.f;
}
__device__ __forceinline__ unsigned short f2bf(float f) {
    union { float f; unsigned int i; } v; v.f = f;
    unsigned int x = v.i;
    return (unsigned short)((x + 0x7fffu + ((x >> 16) & 1u)) >> 16);  // RNE
}
__device__ __forceinline__ void gload16(const void* g, void* l) {
    __builtin_amdgcn_global_load_lds(
        (const __attribute__((address_space(1))) void*)g,
        (__attribute__((address_space(3))) void*)l, 16, 0, 0);
}

// ---------------------------------------------------------------------------
// convw: Wk,Wv -> gamma_kv-folded hi/lo bf16; Wo -> bf16.
// ---------------------------------------------------------------------------
__global__ __launch_bounds__(256)
void convw_kernel(const float* __restrict__ Wk, const float* __restrict__ Wv,
                  const float* __restrict__ Wo, const float* __restrict__ gkv,
                  unsigned short* __restrict__ wk_hi, unsigned short* __restrict__ wk_lo,
                  unsigned short* __restrict__ wv_hi, unsigned short* __restrict__ wv_lo,
                  unsigned short* __restrict__ wo_b)
{
    const int e   = (blockIdx.x * 256 + threadIdx.x) * 4;
    const int sel = e >> 20;
    const int off = e & 0xFFFFF;
    const float* src = sel == 0 ? Wk : sel == 1 ? Wv : Wo;
    float4 v = *(const float4*)(src + off);
    if (sel < 2) {
        float4 g = *(const float4*)(gkv + (off & 1023));
        v.x *= g.x; v.y *= g.y; v.z *= g.z; v.w *= g.w;
        ushort4 h, l;
        h.x = f2bf(v.x); l.x = f2bf(v.x - bf2f(h.x));
        h.y = f2bf(v.y); l.y = f2bf(v.y - bf2f(h.y));
        h.z = f2bf(v.z); l.z = f2bf(v.z - bf2f(h.z));
        h.w = f2bf(v.w); l.w = f2bf(v.w - bf2f(h.w));
        unsigned short* hi = sel == 0 ? wk_hi : wv_hi;
        unsigned short* lo = sel == 0 ? wk_lo : wv_lo;
        *(ushort4*)(hi + off) = h;
        *(ushort4*)(lo + off) = l;
    } else {
        ushort4 o;
        o.x = f2bf(v.x); o.y = f2bf(v.y); o.z = f2bf(v.z); o.w = f2bf(v.w);
        *(ushort4*)(wo_b + off) = o;
    }
}

// ---------------------------------------------------------------------------
// transq: wqT[i][c] = gamma_q[i] * Wq[c][i], split hi/lo bf16.
// ---------------------------------------------------------------------------
__global__ __launch_bounds__(256)
void transq_kernel(const float* __restrict__ Wq, const float* __restrict__ gq,
                   unsigned short* __restrict__ th, unsigned short* __restrict__ tl)
{
    __shared__ float tile[64][65];
    const int c0 = (blockIdx.x & 15) * 64;
    const int i0 = (blockIdx.x >> 4) * 64;
    const int tid = threadIdx.x;
#pragma unroll
    for (int j = 0; j < 4; ++j) {
        const int e  = tid + j * 256;
        const int rl = e >> 4;
        const int q4 = e & 15;
        float4 v = *(const float4*)(Wq + (long)(c0 + rl) * 1024 + i0 + q4 * 4);
        tile[q4 * 4 + 0][rl] = v.x;
        tile[q4 * 4 + 1][rl] = v.y;
        tile[q4 * 4 + 2][rl] = v.z;
        tile[q4 * 4 + 3][rl] = v.w;
    }
    __syncthreads();
#pragma unroll
    for (int j = 0; j < 4; ++j) {
        const int e  = tid + j * 256;
        const int il = e >> 4;
        const int s4 = e & 15;
        const float g = gq[i0 + il];
        float v0 = tile[il][s4 * 4 + 0] * g;
        float v1 = tile[il][s4 * 4 + 1] * g;
        float v2 = tile[il][s4 * 4 + 2] * g;
        float v3 = tile[il][s4 * 4 + 3] * g;
        ushort4 hh, ll;
        hh.x = f2bf(v0); ll.x = f2bf(v0 - bf2f(hh.x));
        hh.y = f2bf(v1); ll.y = f2bf(v1 - bf2f(hh.y));
        hh.z = f2bf(v2); ll.z = f2bf(v2 - bf2f(hh.z));
        hh.w = f2bf(v3); ll.w = f2bf(v3 - bf2f(hh.w));
        const long o = (long)(i0 + il) * 1024 + c0 + s4 * 4;
        *(ushort4*)(th + o) = hh;
        *(ushort4*)(tl + o) = ll;
    }
}

// ---------------------------------------------------------------------------
// RMSNorm + split for ctx rows.
// ---------------------------------------------------------------------------
__global__ __launch_bounds__(256)
void rms_split_kernel(const float* __restrict__ x,
                      unsigned short* __restrict__ xh, unsigned short* __restrict__ xl)
{
    const long row = blockIdx.x;
    float4 v = ((const float4*)(x + row * D_DIM))[threadIdx.x];
    float ss = v.x*v.x + v.y*v.y + v.z*v.z + v.w*v.w;
#pragma unroll
    for (int m = 32; m; m >>= 1) ss += __shfl_xor(ss, m);
    __shared__ float red[4];
    if ((threadIdx.x & 63) == 0) red[threadIdx.x >> 6] = ss;
    __syncthreads();
    const float tot = red[0] + red[1] + red[2] + red[3];
    const float scale = rsqrtf(tot * (1.0f / 1024.0f) + 1.1920929e-07f);
    v.x *= scale; v.y *= scale; v.z *= scale; v.w *= scale;
    ushort4 h, l;
    h.x = f2bf(v.x); l.x = f2bf(v.x - bf2f(h.x));
    h.y = f2bf(v.y); l.y = f2bf(v.y - bf2f(h.y));
    h.z = f2bf(v.z); l.z = f2bf(v.z - bf2f(h.z));
    h.w = f2bf(v.w); l.w = f2bf(v.w - bf2f(h.w));
    *(ushort4*)(xh + row * D_DIM + threadIdx.x * 4) = h;
    *(ushort4*)(xl + row * D_DIM + threadIdx.x * 4) = l;
}

// ---------------------------------------------------------------------------
// gemm_kv: z=0: k split-precision -> kh/kl bf16. z=1: v ~= ch@Wv'_hi^T -> f32.
// ---------------------------------------------------------------------------
__global__ __launch_bounds__(256)
void gemm_kv(const unsigned short* __restrict__ ch, const unsigned short* __restrict__ cl,
             const unsigned short* __restrict__ wkh, const unsigned short* __restrict__ wkl,
             const unsigned short* __restrict__ wvh,
             unsigned short* __restrict__ kh, unsigned short* __restrict__ kl,
             float* __restrict__ v_f)
{
    __shared__ unsigned short Ah[4096], Al[4096], Bh[4096], Bl[4096];
    const bool full = (blockIdx.z == 0);
    const unsigned short* Bhp = full ? wkh : wvh;
    const unsigned short* Blp = wkl;

    const int tid = threadIdx.x, lane = tid & 63, wave = tid >> 6;
    const int wm = wave >> 1, wn = wave & 1;
    const long Arow0 = (long)blockIdx.y * 128;
    const int  Brow0 = blockIdx.x * 128;
    const int fr = lane & 15, ks = lane >> 4;
    const int ksz = (ks ^ ((fr >> 1) & 3)) << 4;
    const int kq  = ((tid & 3) ^ ((tid >> 3) & 3)) * 8;
    const int srow = tid >> 2;

    const long a_off0 = (Arow0 + srow) * D_DIM + kq;
    const long a_off1 = (Arow0 + srow + 64) * D_DIM + kq;
    const long b_off0 = (long)(Brow0 + srow) * D_DIM + kq;
    const long b_off1 = (long)(Brow0 + srow + 64) * D_DIM + kq;

    f32x4 acc[4][4] = {};
    char* AhB = (char*)Ah; char* AlB = (char*)Al;
    char* BhB = (char*)Bh; char* BlB = (char*)Bl;

    for (int kt = 0; kt < 32; ++kt) {
        const int k0 = kt * 32;
        gload16(ch + a_off0 + k0, AhB + tid * 16);
        gload16(ch + a_off1 + k0, AhB + 4096 + tid * 16);
        gload16(Bhp + b_off0 + k0, BhB + tid * 16);
        gload16(Bhp + b_off1 + k0, BhB + 4096 + tid * 16);
        if (full) {
            gload16(cl + a_off0 + k0, AlB + tid * 16);
            gload16(cl + a_off1 + k0, AlB + 4096 + tid * 16);
            gload16(Blp + b_off0 + k0, BlB + tid * 16);
            gload16(Blp + b_off1 + k0, BlB + 4096 + tid * 16);
        }
        __syncthreads();

        short8 ah[4], al[4], bh[4], bl[4];
#pragma unroll
        for (int mi = 0; mi < 4; ++mi) {
            const int aoff = (wm * 64 + mi * 16 + fr) * 64 + ksz;
            ah[mi] = *(const short8*)(AhB + aoff);
            if (full) al[mi] = *(const short8*)(AlB + aoff);
        }
#pragma unroll
        for (int ni = 0; ni < 4; ++ni) {
            const int boff = (wn * 64 + ni * 16 + fr) * 64 + ksz;
            bh[ni] = *(const short8*)(BhB + boff);
            if (full) bl[ni] = *(const short8*)(BlB + boff);
        }
#pragma unroll
        for (int mi = 0; mi < 4; ++mi)
#pragma unroll
            for (int ni = 0; ni < 4; ++ni) {
                acc[mi][ni] = __builtin_amdgcn_mfma_f32_16x16x32_bf16(ah[mi], bh[ni], acc[mi][ni], 0, 0, 0);
                if (full) {
                    acc[mi][ni] = __builtin_amdgcn_mfma_f32_16x16x32_bf16(al[mi], bh[ni], acc[mi][ni], 0, 0, 0);
                    acc[mi][ni] = __builtin_amdgcn_mfma_f32_16x16x32_bf16(ah[mi], bl[ni], acc[mi][ni], 0, 0, 0);
                }
            }
        __syncthreads();
    }

    const int c = lane & 15, r0 = (lane >> 4) * 4;
#pragma unroll
    for (int mi = 0; mi < 4; ++mi)
#pragma unroll
        for (int ni = 0; ni < 4; ++ni)
#pragma unroll
            for (int j = 0; j < 4; ++j) {
                const long row = Arow0 + wm * 64 + mi * 16 + r0 + j;
                const int  col = Brow0 + wn * 64 + ni * 16 + c;
                const float val = acc[mi][ni][j];
                if (full) {
                    const unsigned short hh = f2bf(val);
                    kh[row * D_DIM + col] = hh;
                    kl[row * D_DIM + col] = f2bf(val - bf2f(hh));
                } else {
                    v_f[row * D_DIM + col] = val;
                }
            }
}

// ---------------------------------------------------------------------------
// gemm_U: U[b,p,h][i] = sum_d (kh+kl)[(b,p),h*64+d]*(wqT_h+l)[i,h*64+d],
// epilogue -> bf16 hi/lo (Uh/Ul).
// ---------------------------------------------------------------------------
__global__ __launch_bounds__(256)
void gemm_U(const unsigned short* __restrict__ kh, const unsigned short* __restrict__ kl,
            const unsigned short* __restrict__ th, const unsigned short* __restrict__ tl,
            unsigned short* __restrict__ Uh, unsigned short* __restrict__ Ul)
{
    __shared__ unsigned short Ah[4096], Al[4096], Bh[4096], Bl[4096];
    const int h = blockIdx.z;
    const int tid = threadIdx.x, lane = tid & 63, wave = tid >> 6;
    const int wm = wave >> 1, wn = wave & 1;
    const long Arow0 = (long)blockIdx.y * 128;
    const int  Brow0 = blockIdx.x * 128;
    const int fr = lane & 15, ks = lane >> 4;
    const int ksz = (ks ^ ((fr >> 1) & 3)) << 4;
    const int kq  = ((tid & 3) ^ ((tid >> 3) & 3)) * 8;
    const int srow = tid >> 2;
    const int kb = h * 64;

    const long a_off0 = (Arow0 + srow) * D_DIM + kb + kq;
    const long a_off1 = (Arow0 + srow + 64) * D_DIM + kb + kq;
    const long b_off0 = (long)(Brow0 + srow) * D_DIM + kb + kq;
    const long b_off1 = (long)(Brow0 + srow + 64) * D_DIM + kb + kq;

    f32x4 acc[4][4] = {};
    char* AhB = (char*)Ah; char* AlB = (char*)Al;
    char* BhB = (char*)Bh; char* BlB = (char*)Bl;

    for (int kt = 0; kt < 2; ++kt) {
        const int k0 = kt * 32;
        gload16(kh + a_off0 + k0, AhB + tid * 16);
        gload16(kh + a_off1 + k0, AhB + 4096 + tid * 16);
        gload16(kl + a_off0 + k0, AlB + tid * 16);
        gload16(kl + a_off1 + k0, AlB + 4096 + tid * 16);
        gload16(th + b_off0 + k0, BhB + tid * 16);
        gload16(th + b_off1 + k0, BhB + 4096 + tid * 16);
        gload16(tl + b_off0 + k0, BlB + tid * 16);
        gload16(tl + b_off1 + k0, BlB + 4096 + tid * 16);
        __syncthreads();

        short8 ah[4], al[4], bh[4], bl[4];
#pragma unroll
        for (int mi = 0; mi < 4; ++mi) {
            const int aoff = (wm * 64 + mi * 16 + fr) * 64 + ksz;
            ah[mi] = *(const short8*)(AhB + aoff);
            al[mi] = *(const short8*)(AlB + aoff);
        }
#pragma unroll
        for (int ni = 0; ni < 4; ++ni) {
            const int boff = (wn * 64 + ni * 16 + fr) * 64 + ksz;
            bh[ni] = *(const short8*)(BhB + boff);
            bl[ni] = *(const short8*)(BlB + boff);
        }
#pragma unroll
        for (int mi = 0; mi < 4; ++mi)
#pragma unroll
            for (int ni = 0; ni < 4; ++ni) {
                acc[mi][ni] = __builtin_amdgcn_mfma_f32_16x16x32_bf16(ah[mi], bh[ni], acc[mi][ni], 0, 0, 0);
                acc[mi][ni] = __builtin_amdgcn_mfma_f32_16x16x32_bf16(al[mi], bh[ni], acc[mi][ni], 0, 0, 0);
                acc[mi][ni] = __builtin_amdgcn_mfma_f32_16x16x32_bf16(ah[mi], bl[ni], acc[mi][ni], 0, 0, 0);
            }
        __syncthreads();
    }

    const int c = lane & 15, r0 = (lane >> 4) * 4;
#pragma unroll
    for (int mi = 0; mi < 4; ++mi)
#pragma unroll
        for (int ni = 0; ni < 4; ++ni)
#pragma unroll
            for (int j = 0; j < 4; ++j) {
                const long row = Arow0 + wm * 64 + mi * 16 + r0 + j;
                const int  col = Brow0 + wn * 64 + ni * 16 + c;
                const float val = acc[mi][ni][j];
                const long o = ((long)row * 16 + h) * 1024 + col;
                const unsigned short hh = f2bf(val);
                Uh[o] = hh;
                Ul[o] = f2bf(val - bf2f(hh));
            }
}

// ---------------------------------------------------------------------------
// score v6: v4 body (r15-validated) with 4-WAY K-SPLIT. Block (pg, mh,
// b+4*ks): K-quarter ks (256 cols, 8 steps). Raw partial dots -> sbuf[ks];
// partial sum(x^2) -> ssbuf[ks]. Grid 2048 -> ~4 working blocks/CU.
// ---------------------------------------------------------------------------
__global__ __launch_bounds__(256)
void score_gemm(const float* __restrict__ x, const int* __restrict__ cidx,
                const unsigned short* __restrict__ Uh, const unsigned short* __restrict__ Ul,
                float* __restrict__ sbuf, float* __restrict__ ssbuf)
{
    const int pg = blockIdx.x;          // 0..63
    const int mh = blockIdx.y;          // 0..1 (tile interleave)
    const int bz = blockIdx.z;          // b = bz&3, ks = bz>>2 (0..3)
    const int b  = bz & 3;
    const int ksp = bz >> 2;
    const int kbase = ksp << 8;         // 0,256,512,768
    const int p0 = pg * 4;
    const int* ci = cidx + (b << 12);
    int l = 0, r = 4096;
    while (l < r) { int m = (l + r) >> 1; if (ci[m] < p0 - 1) l = m + 1; else r = m; }
    const int lo = l;
    r = 4096;
    while (l < r) { int m = (l + r) >> 1; if (ci[m] <= p0 + 4) l = m + 1; else r = m; }
    const int hi = l;
    if (lo + mh * 64 >= hi) return;

    float* const sb = sbuf + (long)ksp * 786432;      // 16384*16*3 per slice
    float* const ssb = ssbuf + (ksp << 14);           // 16384 per slice

    __shared__ unsigned short AhS[2][2048], AlS[2][2048];  // 64 rows x 32 cols
    __shared__ unsigned short UhS[2][2048], UlS[2][2048];

    const int tid = threadIdx.x, lane = tid & 63, wave = tid >> 6;
    const int fr = lane & 15;
    const int ks = lane >> 4;
    const int ksz = (ks ^ ((fr >> 1) & 3)) << 4;

    const int arow = tid >> 2, aq = tid & 3;
    const int aslot = aq ^ ((arow >> 1) & 3);
    const unsigned short* const Uhb = Uh + ((long)((b << 8) + p0) * 16) * 1024 + kbase;
    const unsigned short* const Ulb = Ul + ((long)((b << 8) + p0) * 16) * 1024 + kbase;
    const float* const xb = x + ((long)b << 12) * 1024 + kbase;

    for (int t0 = lo + mh * 64; t0 < hi; t0 += 128) {
        const int tc0 = (t0 + arow < hi) ? (t0 + arow) : (hi - 1);
        const float* xr = xb + (long)tc0 * 1024 + aq * 8;
        float ss = 0.f;

        // ---- prologue: k=0 -> buf 0 ----
        gload16(Uhb + (long)arow * 1024 + aslot * 8, (char*)&UhS[0][0] + tid * 16);
        gload16(Ulb + (long)arow * 1024 + aslot * 8, (char*)&UlS[0][0] + tid * 16);
        {
            const float4 v0 = *(const float4*)(xr);
            const float4 v1 = *(const float4*)(xr + 4);
            ss += v0.x*v0.x + v0.y*v0.y + v0.z*v0.z + v0.w*v0.w
                + v1.x*v1.x + v1.y*v1.y + v1.z*v1.z + v1.w*v1.w;
            short8 hv, lv;
            unsigned short h_;
            h_ = f2bf(v0.x); hv[0] = (short)h_; lv[0] = (short)f2bf(v0.x - bf2f(h_));
            h_ = f2bf(v0.y); hv[1] = (short)h_; lv[1] = (short)f2bf(v0.y - bf2f(h_));
            h_ = f2bf(v0.z); hv[2] = (short)h_; lv[2] = (short)f2bf(v0.z - bf2f(h_));
            h_ = f2bf(v0.w); hv[3] = (short)h_; lv[3] = (short)f2bf(v0.w - bf2f(h_));
            h_ = f2bf(v1.x); hv[4] = (short)h_; lv[4] = (short)f2bf(v1.x - bf2f(h_));
            h_ = f2bf(v1.y); hv[5] = (short)h_; lv[5] = (short)f2bf(v1.y - bf2f(h_));
            h_ = f2bf(v1.z); hv[6] = (short)h_; lv[6] = (short)f2bf(v1.z - bf2f(h_));
            h_ = f2bf(v1.w); hv[7] = (short)h_; lv[7] = (short)f2bf(v1.w - bf2f(h_));
            *(short8*)((char*)&AhS[0][0] + arow * 64 + aslot * 16) = hv;
            *(short8*)((char*)&AlS[0][0] + arow * 64 + aslot * 16) = lv;
        }
        __syncthreads();

        f32x4 acc[4] = {};
        for (int t = 0; t < 8; ++t) {
            const int cur = t & 1, nxt = cur ^ 1;
            float4 v0, v1;
            if (t < 7) {
                const int k0n = (t + 1) * 32;
                gload16(Uhb + (long)arow * 1024 + k0n + aslot * 8, (char*)&UhS[nxt][0] + tid * 16);
                gload16(Ulb + (long)arow * 1024 + k0n + aslot * 8, (char*)&UlS[nxt][0] + tid * 16);
                v0 = *(const float4*)(xr + k0n);
                v1 = *(const float4*)(xr + k0n + 4);
            }

            const int aoff = cur * 4096 + (wave * 16 + fr) * 64 + ksz;
            const short8 ah = *(const short8*)((char*)&AhS[0][0] + aoff);
            const short8 al = *(const short8*)((char*)&AlS[0][0] + aoff);
#pragma unroll
            for (int ni = 0; ni < 4; ++ni) {
                const int boff = cur * 4096 + (ni * 16 + fr) * 64 + ksz;
                const short8 uh = *(const short8*)((char*)&UhS[0][0] + boff);
                const short8 ul = *(const short8*)((char*)&UlS[0][0] + boff);
                acc[ni] = __builtin_amdgcn_mfma_f32_16x16x32_bf16(ah, uh, acc[ni], 0, 0, 0);
                acc[ni] = __builtin_amdgcn_mfma_f32_16x16x32_bf16(al, uh, acc[ni], 0, 0, 0);
                acc[ni] = __builtin_amdgcn_mfma_f32_16x16x32_bf16(ah, ul, acc[ni], 0, 0, 0);
            }

            if (t < 7) {
                ss += v0.x*v0.x + v0.y*v0.y + v0.z*v0.z + v0.w*v0.w
                    + v1.x*v1.x + v1.y*v1.y + v1.z*v1.z + v1.w*v1.w;
                short8 hv, lv;
                unsigned short h_;
                h_ = f2bf(v0.x); hv[0] = (short)h_; lv[0] = (short)f2bf(v0.x - bf2f(h_));
                h_ = f2bf(v0.y); hv[1] = (short)h_; lv[1] = (short)f2bf(v0.y - bf2f(h_));
                h_ = f2bf(v0.z); hv[2] = (short)h_; lv[2] = (short)f2bf(v0.z - bf2f(h_));
                h_ = f2bf(v0.w); hv[3] = (short)h_; lv[3] = (short)f2bf(v0.w - bf2f(h_));
                h_ = f2bf(v1.x); hv[4] = (short)h_; lv[4] = (short)f2bf(v1.x - bf2f(h_));
                h_ = f2bf(v1.y); hv[5] = (short)h_; lv[5] = (short)f2bf(v1.y - bf2f(h_));
                h_ = f2bf(v1.z); hv[6] = (short)h_; lv[6] = (short)f2bf(v1.z - bf2f(h_));
                h_ = f2bf(v1.w); hv[7] = (short)h_; lv[7] = (short)f2bf(v1.w - bf2f(h_));
                *(short8*)((char*)&AhS[0][0] + nxt * 4096 + arow * 64 + aslot * 16) = hv;
                *(short8*)((char*)&AlS[0][0] + nxt * 4096 + arow * 64 + aslot * 16) = lv;
            }
            __syncthreads();
        }

        // ---- partial sum(x^2) over this K-quarter -> ssbuf ----
        ss += __shfl_xor(ss, 1);
        ss += __shfl_xor(ss, 2);
        if (aq == 0 && t0 + arow < hi)
            ssb[(b << 12) + t0 + arow] = ss;

        // ---- epilogue: scatter raw partial dots ----
        const int hcol = lane & 15;
        const int r0j = (lane >> 4) * 4;
#pragma unroll
        for (int j = 0; j < 4; ++j) {
            const int trow = t0 + wave * 16 + r0j + j;
            if (trow < hi) {
                const long tg = ((long)b << 12) + trow;
                const int idx = ci[trow];
#pragma unroll
                for (int ni = 0; ni < 4; ++ni) {
                    const int dp = p0 + ni - idx + 1;
                    if (dp >= 0 && dp <= 2)
                        sb[(tg * 16 + hcol) * 3 + dp] = acc[ni][j];
                }
            }
        }
        __syncthreads();   // LDS reuse safety before next tile's prologue
    }
}

// ---------------------------------------------------------------------------
// attnout: dot = sum of 4 K-quarters; s = dot*rsqrt(mean xx+eps)/8;
// w=relu(s)^2, normalize, out = sum w*v. ao bf16.
// ---------------------------------------------------------------------------
__global__ __launch_bounds__(256)
void attnout_kernel(const float* __restrict__ sbuf, const float* __restrict__ ssbuf,
                    const float* __restrict__ vf, const int* __restrict__ cidx,
                    unsigned short* __restrict__ ao)
{
    const int tid = threadIdx.x;
    const int tg = tid >> 4, h = tid & 15;
    const int t = blockIdx.x * 16 + tg;
    const int b = t >> 12;
    const int idx = cidx[t];
    const long so = ((long)t * 16 + h) * 3;
    const float* sb0 = sbuf + so;
    const float* sb1 = sb0 + 786432;
    const float* sb2 = sb1 + 786432;
    const float* sb3 = sb2 + 786432;
    const float ssum = ssbuf[t] + ssbuf[t + 16384] + ssbuf[t + 32768] + ssbuf[t + 49152];
    const float scale = rsqrtf(ssum * (1.0f / 1024.0f) + 1.1920929e-07f) * 0.125f;
    float w0 = 0.f, w1 = 0.f, w2 = 0.f, wsum = 0.f;
    if (idx - 1 >= 0) {
        float s = (sb0[0] + sb1[0] + sb2[0] + sb3[0]) * scale;
        if (s > 0.f) { w0 = s * s; wsum += w0; }
    }
    {
        float s = (sb0[1] + sb1[1] + sb2[1] + sb3[1]) * scale;
        if (s > 0.f) { w1 = s * s; wsum += w1; }
    }
    if (idx + 1 < 256) {
        float s = (sb0[2] + sb1[2] + sb2[2] + sb3[2]) * scale;
        if (s > 0.f) { w2 = s * s; wsum += w2; }
    }
    const float inv = 1.0f / fmaxf(wsum, 1e-6f);
    w0 *= inv; w1 *= inv; w2 *= inv;
    const int p0 = idx > 0 ? idx - 1 : 0;
    const int p2 = idx < 255 ? idx + 1 : 255;
    const float4* v0 = (const float4*)(vf + ((long)(b * 256 + p0)) * 1024 + h * 64);
    const float4* v1 = (const float4*)(vf + ((long)(b * 256 + idx)) * 1024 + h * 64);
    const float4* v2 = (const float4*)(vf + ((long)(b * 256 + p2)) * 1024 + h * 64);
    ushort4* aop = (ushort4*)(ao + (long)t * 1024 + h * 64);
#pragma unroll
    for (int q = 0; q < 16; ++q) {
        float4 a0 = v0[q], a1 = v1[q], a2 = v2[q];
        ushort4 o;
        o.x = f2bf(w0 * a0.x + w1 * a1.x + w2 * a2.x);
        o.y = f2bf(w0 * a0.y + w1 * a1.y + w2 * a2.y);
        o.z = f2bf(w0 * a0.z + w1 * a1.z + w2 * a2.z);
        o.w = f2bf(w0 * a0.w + w1 * a1.w + w2 * a2.w);
        aop[q] = o;
    }
}

// ---------------------------------------------------------------------------
// out = x + ao @ Wo^T, 256x256, swizzled, 8-PHASE deep-pipelined (r15, win).
// ---------------------------------------------------------------------------
__global__ __launch_bounds__(512, 2)
void gemm_out256(const unsigned short* __restrict__ A,
                 const unsigned short* __restrict__ W,
                 float* __restrict__ C, const float* __restrict__ resid)
{
    __shared__ unsigned short As[4][8192];
    __shared__ unsigned short Bs[4][8192];

    const int lin = blockIdx.x;
    const int bx = (lin >> 3) & 3;
    const int by = ((lin >> 5) << 3) | (lin & 7);
    const long row0 = (long)by * 256;
    const int  col0 = bx * 256;

    const int tid = threadIdx.x, lane = tid & 63, wave = tid >> 6;
    const int wm = wave >> 2, wn = wave & 3;
    const int fr = lane & 15, ks = lane >> 4;
    const int ksz = (ks ^ ((fr >> 1) & 3)) << 4;
    const int kq  = ((tid & 3) ^ ((tid >> 3) & 3)) * 8;
    const int srow = tid >> 2;

    const long a_off0 = (row0 + srow) * D_DIM + kq;
    const long a_off1 = (row0 + 128 + srow) * D_DIM + kq;
    const long b_off0 = (long)(col0 + srow) * D_DIM + kq;
    const long b_off1 = (long)(col0 + 128 + srow) * D_DIM + kq;

    f32x4 acc[8][4] = {};

#define STAGE_A(X) do { const int kofs_ = (X) * 32;                          \
    char* base_ = (char*)&As[(X) & 3][0];                                    \
    gload16(A + a_off0 + kofs_, base_ + tid * 16);                           \
    gload16(A + a_off1 + kofs_, base_ + 8192 + tid * 16); } while (0)
#define STAGE_B(X) do { const int kofs_ = (X) * 32;                          \
    char* base_ = (char*)&Bs[(X) & 3][0];                                    \
    gload16(W + b_off0 + kofs_, base_ + tid * 16);                           \
    gload16(W + b_off1 + kofs_, base_ + 8192 + tid * 16); } while (0)

    STAGE_A(0); STAGE_B(0); STAGE_A(1); STAGE_B(1); STAGE_A(2); STAGE_B(2);
    asm volatile("s_waitcnt vmcnt(4)" ::: "memory");
    __builtin_amdgcn_s_barrier();
    __builtin_amdgcn_sched_barrier(0);

    short8 bfrag[4];

    for (int i = 0; i < 8; ++i) {
        const int Tb = i * 4;
        const bool last = (i == 7);
#pragma unroll
        for (int ph = 0; ph < 8; ++ph) {
            const int tp = ph >> 1;
            const int h  = ph & 1;
            const int rg = tp;
            if (h == 0) {
#pragma unroll
                for (int ni = 0; ni < 4; ++ni)
                    bfrag[ni] = *(const short8*)((char*)&Bs[rg][0] +
                                (wn * 64 + ni * 16 + fr) * 64 + ksz);
            }
            short8 afrag[4];
#pragma unroll
            for (int mi = 0; mi < 4; ++mi)
                afrag[mi] = *(const short8*)((char*)&As[rg][0] +
                            (wm * 128 + h * 64 + mi * 16 + fr) * 64 + ksz);
            {
                const int SX = Tb + 3 + tp;
                if (SX < 32) {
                    if (h == 0) STAGE_A(SX); else STAGE_B(SX);
                }
            }
            if (ph == 3) {
                if (last) asm volatile("s_waitcnt vmcnt(0)" ::: "memory");
                else      asm volatile("s_waitcnt vmcnt(4)" ::: "memory");
            } else if (ph == 7) {
                if (!last) asm volatile("s_waitcnt vmcnt(4)" ::: "memory");
            }
            __builtin_amdgcn_s_barrier();
            asm volatile("s_waitcnt lgkmcnt(0)" ::: "memory");
            __builtin_amdgcn_sched_barrier(0);
            __builtin_amdgcn_s_setprio(1);
#pragma unroll
            for (int mi = 0; mi < 4; ++mi)
#pragma unroll
                for (int ni = 0; ni < 4; ++ni)
                    acc[h * 4 + mi][ni] = __builtin_amdgcn_mfma_f32_16x16x32_bf16(
                        afrag[mi], bfrag[ni], acc[h * 4 + mi][ni], 0, 0, 0);
            __builtin_amdgcn_s_setprio(0);
            __builtin_amdgcn_sched_barrier(0);
            __builtin_amdgcn_s_barrier();
            __builtin_amdgcn_sched_barrier(0);
        }
    }
#undef STAGE_A
#undef STAGE_B

    const int c = lane & 15, rg2 = lane >> 4;
#pragma unroll
    for (int mi = 0; mi < 8; ++mi)
#pragma unroll
        for (int ni = 0; ni < 4; ++ni)
#pragma unroll
            for (int j = 0; j < 4; ++j) {
                const long row = row0 + wm * 128 + mi * 16 + rg2 * 4 + j;
                const int  col = col0 + wn * 64 + ni * 16 + c;
                C[row * D_DIM + col] = resid[row * D_DIM + col] + acc[mi][ni][j];
            }
}

// ---------------------------------------------------------------------------
extern "C" void kernel_launch(void* const* d_in, const int* in_sizes, int n_in,
                              void* d_out, int out_size, void* d_ws, size_t ws_size,
                              hipStream_t stream)
{
    const float* x    = (const float*)d_in[0];
    const float* ctx  = (const float*)d_in[1];
    const int*   cidx = (const int*)d_in[2];
    const float* gq   = (const float*)d_in[3];
    const float* gkv  = (const float*)d_in[4];
    const float* Wq   = (const float*)d_in[5];
    const float* Wk   = (const float*)d_in[6];
    const float* Wv   = (const float*)d_in[7];
    const float* Wo   = (const float*)d_in[8];
    float* out = (float*)d_out;

    char* ws = (char*)d_ws;
    const size_t MB = 1 << 20;
    unsigned short* wqT_hi = (unsigned short*)(ws + 0 * MB);
    unsigned short* wqT_lo = (unsigned short*)(ws + 2 * MB);
    unsigned short* wk_hi  = (unsigned short*)(ws + 4 * MB);
    unsigned short* wk_lo  = (unsigned short*)(ws + 6 * MB);
    unsigned short* wv_hi  = (unsigned short*)(ws + 8 * MB);
    unsigned short* wv_lo  = (unsigned short*)(ws + 10 * MB);
    unsigned short* wo_b   = (unsigned short*)(ws + 12 * MB);
    unsigned short* ch = (unsigned short*)(ws + 14 * MB);
    unsigned short* cl = (unsigned short*)(ws + 16 * MB);
    unsigned short* kh = (unsigned short*)(ws + 18 * MB);
    unsigned short* kl = (unsigned short*)(ws + 20 * MB);
    float* v_f = (float*)(ws + 22 * MB);                      // 4MB
    unsigned short* Uh = (unsigned short*)(ws + 26 * MB);     // 32MB (26..58)
    unsigned short* Ul = (unsigned short*)(ws + 58 * MB);     // 32MB (58..90)
    unsigned short* ao_b = (unsigned short*)(ws + 26 * MB);   // 32MB, ALIASES Uh
        // (Uh dead after score_gemm; attnout writes ao afterwards)
    float* sbuf  = (float*)(ws + 91 * MB);                    // 4 x 3MB (91..103)
    float* ssbuf = (float*)(ws + 103 * MB);                   // 4 x 64KB; ~104MB

    convw_kernel<<<3072, 256, 0, stream>>>(Wk, Wv, Wo, gkv,
                                           wk_hi, wk_lo, wv_hi, wv_lo, wo_b);
    transq_kernel<<<256, 256, 0, stream>>>(Wq, gq, wqT_hi, wqT_lo);
    rms_split_kernel<<<1024, 256, 0, stream>>>(ctx, ch, cl);
    gemm_kv<<<dim3(8, 8, 2), 256, 0, stream>>>(ch, cl, wk_hi, wk_lo, wv_hi,
                                               kh, kl, v_f);
    gemm_U<<<dim3(8, 8, 16), 256, 0, stream>>>(kh, kl, wqT_hi, wqT_lo, Uh, Ul);
    score_gemm<<<dim3(64, 2, 16), 256, 0, stream>>>(x, cidx, Uh, Ul, sbuf, ssbuf);
    attnout_kernel<<<1024, 256, 0, stream>>>(sbuf, ssbuf, v_f, cidx, ao_b);
    gemm_out256<<<256, 512, 0, stream>>>(ao_b, wo_b, out, x);
}

// Round 18
// 194.906 us; speedup vs baseline: 1.1702x; 1.0187x over previous
//
#include <hip/hip_runtime.h>
#include <hip/hip_bf16.h>
#include <stdint.h>

// B=4, T=4096, K=256, D=1024, H=16, hd=64
#define D_DIM 1024

using f32x4  = __attribute__((ext_vector_type(4))) float;
using short8 = __attribute__((ext_vector_type(8))) short;

__device__ __forceinline__ float bf2f(unsigned short u) {
    union { unsigned int i; float f; } v; v.i = ((unsigned int)u) << 16; return v.f;
}
__device__ __forceinline__ unsigned short f2bf(float f) {
    union { float f; unsigned int i; } v; v.f = f;
    unsigned int x = v.i;
    return (unsigned short)((x + 0x7fffu + ((x >> 16) & 1u)) >> 16);  // RNE
}
__device__ __forceinline__ void gload16(const void* g, void* l) {
    __builtin_amdgcn_global_load_lds(
        (const __attribute__((address_space(1))) void*)g,
        (__attribute__((address_space(3))) void*)l, 16, 0, 0);
}

// ---------------------------------------------------------------------------
// convw: Wk,Wv -> gamma_kv-folded hi/lo bf16; Wo -> bf16.
// ---------------------------------------------------------------------------
__global__ __launch_bounds__(256)
void convw_kernel(const float* __restrict__ Wk, const float* __restrict__ Wv,
                  const float* __restrict__ Wo, const float* __restrict__ gkv,
                  unsigned short* __restrict__ wk_hi, unsigned short* __restrict__ wk_lo,
                  unsigned short* __restrict__ wv_hi, unsigned short* __restrict__ wv_lo,
                  unsigned short* __restrict__ wo_b)
{
    const int e   = (blockIdx.x * 256 + threadIdx.x) * 4;
    const int sel = e >> 20;
    const int off = e & 0xFFFFF;
    const float* src = sel == 0 ? Wk : sel == 1 ? Wv : Wo;
    float4 v = *(const float4*)(src + off);
    if (sel < 2) {
        float4 g = *(const float4*)(gkv + (off & 1023));
        v.x *= g.x; v.y *= g.y; v.z *= g.z; v.w *= g.w;
        ushort4 h, l;
        h.x = f2bf(v.x); l.x = f2bf(v.x - bf2f(h.x));
        h.y = f2bf(v.y); l.y = f2bf(v.y - bf2f(h.y));
        h.z = f2bf(v.z); l.z = f2bf(v.z - bf2f(h.z));
        h.w = f2bf(v.w); l.w = f2bf(v.w - bf2f(h.w));
        unsigned short* hi = sel == 0 ? wk_hi : wv_hi;
        unsigned short* lo = sel == 0 ? wk_lo : wv_lo;
        *(ushort4*)(hi + off) = h;
        *(ushort4*)(lo + off) = l;
    } else {
        ushort4 o;
        o.x = f2bf(v.x); o.y = f2bf(v.y); o.z = f2bf(v.z); o.w = f2bf(v.w);
        *(ushort4*)(wo_b + off) = o;
    }
}

// ---------------------------------------------------------------------------
// transq: wqT[i][c] = gamma_q[i] * Wq[c][i], split hi/lo bf16.
// ---------------------------------------------------------------------------
__global__ __launch_bounds__(256)
void transq_kernel(const float* __restrict__ Wq, const float* __restrict__ gq,
                   unsigned short* __restrict__ th, unsigned short* __restrict__ tl)
{
    __shared__ float tile[64][65];
    const int c0 = (blockIdx.x & 15) * 64;
    const int i0 = (blockIdx.x >> 4) * 64;
    const int tid = threadIdx.x;
#pragma unroll
    for (int j = 0; j < 4; ++j) {
        const int e  = tid + j * 256;
        const int rl = e >> 4;
        const int q4 = e & 15;
        float4 v = *(const float4*)(Wq + (long)(c0 + rl) * 1024 + i0 + q4 * 4);
        tile[q4 * 4 + 0][rl] = v.x;
        tile[q4 * 4 + 1][rl] = v.y;
        tile[q4 * 4 + 2][rl] = v.z;
        tile[q4 * 4 + 3][rl] = v.w;
    }
    __syncthreads();
#pragma unroll
    for (int j = 0; j < 4; ++j) {
        const int e  = tid + j * 256;
        const int il = e >> 4;
        const int s4 = e & 15;
        const float g = gq[i0 + il];
        float v0 = tile[il][s4 * 4 + 0] * g;
        float v1 = tile[il][s4 * 4 + 1] * g;
        float v2 = tile[il][s4 * 4 + 2] * g;
        float v3 = tile[il][s4 * 4 + 3] * g;
        ushort4 hh, ll;
        hh.x = f2bf(v0); ll.x = f2bf(v0 - bf2f(hh.x));
        hh.y = f2bf(v1); ll.y = f2bf(v1 - bf2f(hh.y));
        hh.z = f2bf(v2); ll.z = f2bf(v2 - bf2f(hh.z));
        hh.w = f2bf(v3); ll.w = f2bf(v3 - bf2f(hh.w));
        const long o = (long)(i0 + il) * 1024 + c0 + s4 * 4;
        *(ushort4*)(th + o) = hh;
        *(ushort4*)(tl + o) = ll;
    }
}

// ---------------------------------------------------------------------------
// RMSNorm + split for ctx rows.
// ---------------------------------------------------------------------------
__global__ __launch_bounds__(256)
void rms_split_kernel(const float* __restrict__ x,
                      unsigned short* __restrict__ xh, unsigned short* __restrict__ xl)
{
    const long row = blockIdx.x;
    float4 v = ((const float4*)(x + row * D_DIM))[threadIdx.x];
    float ss = v.x*v.x + v.y*v.y + v.z*v.z + v.w*v.w;
#pragma unroll
    for (int m = 32; m; m >>= 1) ss += __shfl_xor(ss, m);
    __shared__ float red[4];
    if ((threadIdx.x & 63) == 0) red[threadIdx.x >> 6] = ss;
    __syncthreads();
    const float tot = red[0] + red[1] + red[2] + red[3];
    const float scale = rsqrtf(tot * (1.0f / 1024.0f) + 1.1920929e-07f);
    v.x *= scale; v.y *= scale; v.z *= scale; v.w *= scale;
    ushort4 h, l;
    h.x = f2bf(v.x); l.x = f2bf(v.x - bf2f(h.x));
    h.y = f2bf(v.y); l.y = f2bf(v.y - bf2f(h.y));
    h.z = f2bf(v.z); l.z = f2bf(v.z - bf2f(h.z));
    h.w = f2bf(v.w); l.w = f2bf(v.w - bf2f(h.w));
    *(ushort4*)(xh + row * D_DIM + threadIdx.x * 4) = h;
    *(ushort4*)(xl + row * D_DIM + threadIdx.x * 4) = l;
}

// ---------------------------------------------------------------------------
// bounds: per (b,p): lo = first i with ci[i] >= p-1, hi = first i with
// ci[i] > p+1. 4 blocks x 256 threads; searches run in parallel (L2-hot).
// ---------------------------------------------------------------------------
__global__ __launch_bounds__(256)
void bounds_kernel(const int* __restrict__ cidx, int2* __restrict__ bounds)
{
    const int b = blockIdx.x;
    const int p = threadIdx.x;
    const int* ci = cidx + (b << 12);
    int l = 0, r = 4096;
    while (l < r) { int m = (l + r) >> 1; if (ci[m] < p - 1) l = m + 1; else r = m; }
    const int lo = l;
    r = 4096;
    while (l < r) { int m = (l + r) >> 1; if (ci[m] <= p + 1) l = m + 1; else r = m; }
    bounds[(b << 8) + p] = make_int2(lo, l);
}

// ---------------------------------------------------------------------------
// gemm_kv: z=0: k split-precision -> kh/kl bf16. z=1: v ~= ch@Wv'_hi^T -> f32.
// ---------------------------------------------------------------------------
__global__ __launch_bounds__(256)
void gemm_kv(const unsigned short* __restrict__ ch, const unsigned short* __restrict__ cl,
             const unsigned short* __restrict__ wkh, const unsigned short* __restrict__ wkl,
             const unsigned short* __restrict__ wvh,
             unsigned short* __restrict__ kh, unsigned short* __restrict__ kl,
             float* __restrict__ v_f)
{
    __shared__ unsigned short Ah[4096], Al[4096], Bh[4096], Bl[4096];
    const bool full = (blockIdx.z == 0);
    const unsigned short* Bhp = full ? wkh : wvh;
    const unsigned short* Blp = wkl;

    const int tid = threadIdx.x, lane = tid & 63, wave = tid >> 6;
    const int wm = wave >> 1, wn = wave & 1;
    const long Arow0 = (long)blockIdx.y * 128;
    const int  Brow0 = blockIdx.x * 128;
    const int fr = lane & 15, ks = lane >> 4;
    const int ksz = (ks ^ ((fr >> 1) & 3)) << 4;
    const int kq  = ((tid & 3) ^ ((tid >> 3) & 3)) * 8;
    const int srow = tid >> 2;

    const long a_off0 = (Arow0 + srow) * D_DIM + kq;
    const long a_off1 = (Arow0 + srow + 64) * D_DIM + kq;
    const long b_off0 = (long)(Brow0 + srow) * D_DIM + kq;
    const long b_off1 = (long)(Brow0 + srow + 64) * D_DIM + kq;

    f32x4 acc[4][4] = {};
    char* AhB = (char*)Ah; char* AlB = (char*)Al;
    char* BhB = (char*)Bh; char* BlB = (char*)Bl;

    for (int kt = 0; kt < 32; ++kt) {
        const int k0 = kt * 32;
        gload16(ch + a_off0 + k0, AhB + tid * 16);
        gload16(ch + a_off1 + k0, AhB + 4096 + tid * 16);
        gload16(Bhp + b_off0 + k0, BhB + tid * 16);
        gload16(Bhp + b_off1 + k0, BhB + 4096 + tid * 16);
        if (full) {
            gload16(cl + a_off0 + k0, AlB + tid * 16);
            gload16(cl + a_off1 + k0, AlB + 4096 + tid * 16);
            gload16(Blp + b_off0 + k0, BlB + tid * 16);
            gload16(Blp + b_off1 + k0, BlB + 4096 + tid * 16);
        }
        __syncthreads();

        short8 ah[4], al[4], bh[4], bl[4];
#pragma unroll
        for (int mi = 0; mi < 4; ++mi) {
            const int aoff = (wm * 64 + mi * 16 + fr) * 64 + ksz;
            ah[mi] = *(const short8*)(AhB + aoff);
            if (full) al[mi] = *(const short8*)(AlB + aoff);
        }
#pragma unroll
        for (int ni = 0; ni < 4; ++ni) {
            const int boff = (wn * 64 + ni * 16 + fr) * 64 + ksz;
            bh[ni] = *(const short8*)(BhB + boff);
            if (full) bl[ni] = *(const short8*)(BlB + boff);
        }
#pragma unroll
        for (int mi = 0; mi < 4; ++mi)
#pragma unroll
            for (int ni = 0; ni < 4; ++ni) {
                acc[mi][ni] = __builtin_amdgcn_mfma_f32_16x16x32_bf16(ah[mi], bh[ni], acc[mi][ni], 0, 0, 0);
                if (full) {
                    acc[mi][ni] = __builtin_amdgcn_mfma_f32_16x16x32_bf16(al[mi], bh[ni], acc[mi][ni], 0, 0, 0);
                    acc[mi][ni] = __builtin_amdgcn_mfma_f32_16x16x32_bf16(ah[mi], bl[ni], acc[mi][ni], 0, 0, 0);
                }
            }
        __syncthreads();
    }

    const int c = lane & 15, r0 = (lane >> 4) * 4;
#pragma unroll
    for (int mi = 0; mi < 4; ++mi)
#pragma unroll
        for (int ni = 0; ni < 4; ++ni)
#pragma unroll
            for (int j = 0; j < 4; ++j) {
                const long row = Arow0 + wm * 64 + mi * 16 + r0 + j;
                const int  col = Brow0 + wn * 64 + ni * 16 + c;
                const float val = acc[mi][ni][j];
                if (full) {
                    const unsigned short hh = f2bf(val);
                    kh[row * D_DIM + col] = hh;
                    kl[row * D_DIM + col] = f2bf(val - bf2f(hh));
                } else {
                    v_f[row * D_DIM + col] = val;
                }
            }
}

// ---------------------------------------------------------------------------
// gemm_U: U[b,p,h][i] = sum_d (kh+kl)[(b,p),h*64+d]*(wqT_h+l)[i,h*64+d],
// epilogue -> bf16 hi/lo (Uh/Ul).
// ---------------------------------------------------------------------------
__global__ __launch_bounds__(256)
void gemm_U(const unsigned short* __restrict__ kh, const unsigned short* __restrict__ kl,
            const unsigned short* __restrict__ th, const unsigned short* __restrict__ tl,
            unsigned short* __restrict__ Uh, unsigned short* __restrict__ Ul)
{
    __shared__ unsigned short Ah[4096], Al[4096], Bh[4096], Bl[4096];
    const int h = blockIdx.z;
    const int tid = threadIdx.x, lane = tid & 63, wave = tid >> 6;
    const int wm = wave >> 1, wn = wave & 1;
    const long Arow0 = (long)blockIdx.y * 128;
    const int  Brow0 = blockIdx.x * 128;
    const int fr = lane & 15, ks = lane >> 4;
    const int ksz = (ks ^ ((fr >> 1) & 3)) << 4;
    const int kq  = ((tid & 3) ^ ((tid >> 3) & 3)) * 8;
    const int srow = tid >> 2;
    const int kb = h * 64;

    const long a_off0 = (Arow0 + srow) * D_DIM + kb + kq;
    const long a_off1 = (Arow0 + srow + 64) * D_DIM + kb + kq;
    const long b_off0 = (long)(Brow0 + srow) * D_DIM + kb + kq;
    const long b_off1 = (long)(Brow0 + srow + 64) * D_DIM + kb + kq;

    f32x4 acc[4][4] = {};
    char* AhB = (char*)Ah; char* AlB = (char*)Al;
    char* BhB = (char*)Bh; char* BlB = (char*)Bl;

    for (int kt = 0; kt < 2; ++kt) {
        const int k0 = kt * 32;
        gload16(kh + a_off0 + k0, AhB + tid * 16);
        gload16(kh + a_off1 + k0, AhB + 4096 + tid * 16);
        gload16(kl + a_off0 + k0, AlB + tid * 16);
        gload16(kl + a_off1 + k0, AlB + 4096 + tid * 16);
        gload16(th + b_off0 + k0, BhB + tid * 16);
        gload16(th + b_off1 + k0, BhB + 4096 + tid * 16);
        gload16(tl + b_off0 + k0, BlB + tid * 16);
        gload16(tl + b_off1 + k0, BlB + 4096 + tid * 16);
        __syncthreads();

        short8 ah[4], al[4], bh[4], bl[4];
#pragma unroll
        for (int mi = 0; mi < 4; ++mi) {
            const int aoff = (wm * 64 + mi * 16 + fr) * 64 + ksz;
            ah[mi] = *(const short8*)(AhB + aoff);
            al[mi] = *(const short8*)(AlB + aoff);
        }
#pragma unroll
        for (int ni = 0; ni < 4; ++ni) {
            const int boff = (wn * 64 + ni * 16 + fr) * 64 + ksz;
            bh[ni] = *(const short8*)(BhB + boff);
            bl[ni] = *(const short8*)(BlB + boff);
        }
#pragma unroll
        for (int mi = 0; mi < 4; ++mi)
#pragma unroll
            for (int ni = 0; ni < 4; ++ni) {
                acc[mi][ni] = __builtin_amdgcn_mfma_f32_16x16x32_bf16(ah[mi], bh[ni], acc[mi][ni], 0, 0, 0);
                acc[mi][ni] = __builtin_amdgcn_mfma_f32_16x16x32_bf16(al[mi], bh[ni], acc[mi][ni], 0, 0, 0);
                acc[mi][ni] = __builtin_amdgcn_mfma_f32_16x16x32_bf16(ah[mi], bl[ni], acc[mi][ni], 0, 0, 0);
            }
        __syncthreads();
    }

    const int c = lane & 15, r0 = (lane >> 4) * 4;
#pragma unroll
    for (int mi = 0; mi < 4; ++mi)
#pragma unroll
        for (int ni = 0; ni < 4; ++ni)
#pragma unroll
            for (int j = 0; j < 4; ++j) {
                const long row = Arow0 + wm * 64 + mi * 16 + r0 + j;
                const int  col = Brow0 + wn * 64 + ni * 16 + c;
                const float val = acc[mi][ni][j];
                const long o = ((long)row * 16 + h) * 1024 + col;
                const unsigned short hh = f2bf(val);
                Uh[o] = hh;
                Ul[o] = f2bf(val - bf2f(hh));
            }
}

// ---------------------------------------------------------------------------
// score v7: r15-validated v4 body (2-way K-split, 16 steps) with PRECOMPUTED
// bounds (removes ~5k serial cycles of binary search per block).
// Block (pg, mh, b+4*ks): K-half ks (512 cols). Raw partial dots -> sbuf[ks];
// partial sum(x^2) -> ssbuf[ks].
// ---------------------------------------------------------------------------
__global__ __launch_bounds__(256)
void score_gemm(const float* __restrict__ x, const int* __restrict__ cidx,
                const int2* __restrict__ bounds,
                const unsigned short* __restrict__ Uh, const unsigned short* __restrict__ Ul,
                float* __restrict__ sbuf, float* __restrict__ ssbuf)
{
    const int pg = blockIdx.x;          // 0..63
    const int mh = blockIdx.y;          // 0..1 (tile interleave)
    const int bz = blockIdx.z;          // b = bz&3, ks = bz>>2
    const int b  = bz & 3;
    const int ksp = bz >> 2;
    const int kbase = ksp << 9;         // 0 or 512
    const int p0 = pg * 4;
    const int lo = bounds[(b << 8) + p0].x;
    const int hi = bounds[(b << 8) + p0 + 3].y;
    if (lo + mh * 64 >= hi) return;
    const int* ci = cidx + (b << 12);

    float* const sb = sbuf + (long)ksp * 786432;      // 16384*16*3
    float* const ssb = ssbuf + (ksp << 14);           // 16384

    __shared__ unsigned short AhS[2][2048], AlS[2][2048];  // 64 rows x 32 cols
    __shared__ unsigned short UhS[2][2048], UlS[2][2048];

    const int tid = threadIdx.x, lane = tid & 63, wave = tid >> 6;
    const int fr = lane & 15;
    const int ks = lane >> 4;
    const int ksz = (ks ^ ((fr >> 1) & 3)) << 4;

    const int arow = tid >> 2, aq = tid & 3;
    const int aslot = aq ^ ((arow >> 1) & 3);
    const unsigned short* const Uhb = Uh + ((long)((b << 8) + p0) * 16) * 1024 + kbase;
    const unsigned short* const Ulb = Ul + ((long)((b << 8) + p0) * 16) * 1024 + kbase;
    const float* const xb = x + ((long)b << 12) * 1024 + kbase;

    for (int t0 = lo + mh * 64; t0 < hi; t0 += 128) {
        const int tc0 = (t0 + arow < hi) ? (t0 + arow) : (hi - 1);
        const float* xr = xb + (long)tc0 * 1024 + aq * 8;
        float ss = 0.f;

        // ---- prologue: k=0 -> buf 0 ----
        gload16(Uhb + (long)arow * 1024 + aslot * 8, (char*)&UhS[0][0] + tid * 16);
        gload16(Ulb + (long)arow * 1024 + aslot * 8, (char*)&UlS[0][0] + tid * 16);
        {
            const float4 v0 = *(const float4*)(xr);
            const float4 v1 = *(const float4*)(xr + 4);
            ss += v0.x*v0.x + v0.y*v0.y + v0.z*v0.z + v0.w*v0.w
                + v1.x*v1.x + v1.y*v1.y + v1.z*v1.z + v1.w*v1.w;
            short8 hv, lv;
            unsigned short h_;
            h_ = f2bf(v0.x); hv[0] = (short)h_; lv[0] = (short)f2bf(v0.x - bf2f(h_));
            h_ = f2bf(v0.y); hv[1] = (short)h_; lv[1] = (short)f2bf(v0.y - bf2f(h_));
            h_ = f2bf(v0.z); hv[2] = (short)h_; lv[2] = (short)f2bf(v0.z - bf2f(h_));
            h_ = f2bf(v0.w); hv[3] = (short)h_; lv[3] = (short)f2bf(v0.w - bf2f(h_));
            h_ = f2bf(v1.x); hv[4] = (short)h_; lv[4] = (short)f2bf(v1.x - bf2f(h_));
            h_ = f2bf(v1.y); hv[5] = (short)h_; lv[5] = (short)f2bf(v1.y - bf2f(h_));
            h_ = f2bf(v1.z); hv[6] = (short)h_; lv[6] = (short)f2bf(v1.z - bf2f(h_));
            h_ = f2bf(v1.w); hv[7] = (short)h_; lv[7] = (short)f2bf(v1.w - bf2f(h_));
            *(short8*)((char*)&AhS[0][0] + arow * 64 + aslot * 16) = hv;
            *(short8*)((char*)&AlS[0][0] + arow * 64 + aslot * 16) = lv;
        }
        __syncthreads();

        f32x4 acc[4] = {};
        for (int t = 0; t < 16; ++t) {
            const int cur = t & 1, nxt = cur ^ 1;
            float4 v0, v1;
            if (t < 15) {
                const int k0n = (t + 1) * 32;
                gload16(Uhb + (long)arow * 1024 + k0n + aslot * 8, (char*)&UhS[nxt][0] + tid * 16);
                gload16(Ulb + (long)arow * 1024 + k0n + aslot * 8, (char*)&UlS[nxt][0] + tid * 16);
                v0 = *(const float4*)(xr + k0n);
                v1 = *(const float4*)(xr + k0n + 4);
            }

            const int aoff = cur * 4096 + (wave * 16 + fr) * 64 + ksz;
            const short8 ah = *(const short8*)((char*)&AhS[0][0] + aoff);
            const short8 al = *(const short8*)((char*)&AlS[0][0] + aoff);
#pragma unroll
            for (int ni = 0; ni < 4; ++ni) {
                const int boff = cur * 4096 + (ni * 16 + fr) * 64 + ksz;
                const short8 uh = *(const short8*)((char*)&UhS[0][0] + boff);
                const short8 ul = *(const short8*)((char*)&UlS[0][0] + boff);
                acc[ni] = __builtin_amdgcn_mfma_f32_16x16x32_bf16(ah, uh, acc[ni], 0, 0, 0);
                acc[ni] = __builtin_amdgcn_mfma_f32_16x16x32_bf16(al, uh, acc[ni], 0, 0, 0);
                acc[ni] = __builtin_amdgcn_mfma_f32_16x16x32_bf16(ah, ul, acc[ni], 0, 0, 0);
            }

            if (t < 15) {
                ss += v0.x*v0.x + v0.y*v0.y + v0.z*v0.z + v0.w*v0.w
                    + v1.x*v1.x + v1.y*v1.y + v1.z*v1.z + v1.w*v1.w;
                short8 hv, lv;
                unsigned short h_;
                h_ = f2bf(v0.x); hv[0] = (short)h_; lv[0] = (short)f2bf(v0.x - bf2f(h_));
                h_ = f2bf(v0.y); hv[1] = (short)h_; lv[1] = (short)f2bf(v0.y - bf2f(h_));
                h_ = f2bf(v0.z); hv[2] = (short)h_; lv[2] = (short)f2bf(v0.z - bf2f(h_));
                h_ = f2bf(v0.w); hv[3] = (short)h_; lv[3] = (short)f2bf(v0.w - bf2f(h_));
                h_ = f2bf(v1.x); hv[4] = (short)h_; lv[4] = (short)f2bf(v1.x - bf2f(h_));
                h_ = f2bf(v1.y); hv[5] = (short)h_; lv[5] = (short)f2bf(v1.y - bf2f(h_));
                h_ = f2bf(v1.z); hv[6] = (short)h_; lv[6] = (short)f2bf(v1.z - bf2f(h_));
                h_ = f2bf(v1.w); hv[7] = (short)h_; lv[7] = (short)f2bf(v1.w - bf2f(h_));
                *(short8*)((char*)&AhS[0][0] + nxt * 4096 + arow * 64 + aslot * 16) = hv;
                *(short8*)((char*)&AlS[0][0] + nxt * 4096 + arow * 64 + aslot * 16) = lv;
            }
            __syncthreads();
        }

        // ---- partial sum(x^2) over this K-half -> ssbuf ----
        ss += __shfl_xor(ss, 1);
        ss += __shfl_xor(ss, 2);
        if (aq == 0 && t0 + arow < hi)
            ssb[(b << 12) + t0 + arow] = ss;

        // ---- epilogue: scatter raw partial dots ----
        const int hcol = lane & 15;
        const int r0j = (lane >> 4) * 4;
#pragma unroll
        for (int j = 0; j < 4; ++j) {
            const int trow = t0 + wave * 16 + r0j + j;
            if (trow < hi) {
                const long tg = ((long)b << 12) + trow;
                const int idx = ci[trow];
#pragma unroll
                for (int ni = 0; ni < 4; ++ni) {
                    const int dp = p0 + ni - idx + 1;
                    if (dp >= 0 && dp <= 2)
                        sb[(tg * 16 + hcol) * 3 + dp] = acc[ni][j];
                }
            }
        }
        __syncthreads();   // LDS reuse safety before next tile's prologue
    }
}

// ---------------------------------------------------------------------------
// attnout: dot = sum of K-halves; s = dot*rsqrt(mean xx+eps)/8; w=relu(s)^2,
// normalize, out = sum w*v. ao bf16.
// ---------------------------------------------------------------------------
__global__ __launch_bounds__(256)
void attnout_kernel(const float* __restrict__ sbuf, const float* __restrict__ ssbuf,
                    const float* __restrict__ vf, const int* __restrict__ cidx,
                    unsigned short* __restrict__ ao)
{
    const int tid = threadIdx.x;
    const int tg = tid >> 4, h = tid & 15;
    const int t = blockIdx.x * 16 + tg;
    const int b = t >> 12;
    const int idx = cidx[t];
    const float* sb0 = sbuf + ((long)t * 16 + h) * 3;
    const float* sb1 = sb0 + 786432;
    const float ssum = ssbuf[t] + ssbuf[t + 16384];
    const float scale = rsqrtf(ssum * (1.0f / 1024.0f) + 1.1920929e-07f) * 0.125f;
    float w0 = 0.f, w1 = 0.f, w2 = 0.f, wsum = 0.f;
    if (idx - 1 >= 0) { float s = (sb0[0] + sb1[0]) * scale; if (s > 0.f) { w0 = s * s; wsum += w0; } }
    { float s = (sb0[1] + sb1[1]) * scale; if (s > 0.f) { w1 = s * s; wsum += w1; } }
    if (idx + 1 < 256) { float s = (sb0[2] + sb1[2]) * scale; if (s > 0.f) { w2 = s * s; wsum += w2; } }
    const float inv = 1.0f / fmaxf(wsum, 1e-6f);
    w0 *= inv; w1 *= inv; w2 *= inv;
    const int p0 = idx > 0 ? idx - 1 : 0;
    const int p2 = idx < 255 ? idx + 1 : 255;
    const float4* v0 = (const float4*)(vf + ((long)(b * 256 + p0)) * 1024 + h * 64);
    const float4* v1 = (const float4*)(vf + ((long)(b * 256 + idx)) * 1024 + h * 64);
    const float4* v2 = (const float4*)(vf + ((long)(b * 256 + p2)) * 1024 + h * 64);
    ushort4* aop = (ushort4*)(ao + (long)t * 1024 + h * 64);
#pragma unroll
    for (int q = 0; q < 16; ++q) {
        float4 a0 = v0[q], a1 = v1[q], a2 = v2[q];
        ushort4 o;
        o.x = f2bf(w0 * a0.x + w1 * a1.x + w2 * a2.x);
        o.y = f2bf(w0 * a0.y + w1 * a1.y + w2 * a2.y);
        o.z = f2bf(w0 * a0.z + w1 * a1.z + w2 * a2.z);
        o.w = f2bf(w0 * a0.w + w1 * a1.w + w2 * a2.w);
        aop[q] = o;
    }
}

// ---------------------------------------------------------------------------
// out = x + ao @ Wo^T, 256x256, swizzled, 8-PHASE deep-pipelined (r15, win).
// ---------------------------------------------------------------------------
__global__ __launch_bounds__(512, 2)
void gemm_out256(const unsigned short* __restrict__ A,
                 const unsigned short* __restrict__ W,
                 float* __restrict__ C, const float* __restrict__ resid)
{
    __shared__ unsigned short As[4][8192];
    __shared__ unsigned short Bs[4][8192];

    const int lin = blockIdx.x;
    const int bx = (lin >> 3) & 3;
    const int by = ((lin >> 5) << 3) | (lin & 7);
    const long row0 = (long)by * 256;
    const int  col0 = bx * 256;

    const int tid = threadIdx.x, lane = tid & 63, wave = tid >> 6;
    const int wm = wave >> 2, wn = wave & 3;
    const int fr = lane & 15, ks = lane >> 4;
    const int ksz = (ks ^ ((fr >> 1) & 3)) << 4;
    const int kq  = ((tid & 3) ^ ((tid >> 3) & 3)) * 8;
    const int srow = tid >> 2;

    const long a_off0 = (row0 + srow) * D_DIM + kq;
    const long a_off1 = (row0 + 128 + srow) * D_DIM + kq;
    const long b_off0 = (long)(col0 + srow) * D_DIM + kq;
    const long b_off1 = (long)(col0 + 128 + srow) * D_DIM + kq;

    f32x4 acc[8][4] = {};

#define STAGE_A(X) do { const int kofs_ = (X) * 32;                          \
    char* base_ = (char*)&As[(X) & 3][0];                                    \
    gload16(A + a_off0 + kofs_, base_ + tid * 16);                           \
    gload16(A + a_off1 + kofs_, base_ + 8192 + tid * 16); } while (0)
#define STAGE_B(X) do { const int kofs_ = (X) * 32;                          \
    char* base_ = (char*)&Bs[(X) & 3][0];                                    \
    gload16(W + b_off0 + kofs_, base_ + tid * 16);                           \
    gload16(W + b_off1 + kofs_, base_ + 8192 + tid * 16); } while (0)

    STAGE_A(0); STAGE_B(0); STAGE_A(1); STAGE_B(1); STAGE_A(2); STAGE_B(2);
    asm volatile("s_waitcnt vmcnt(4)" ::: "memory");
    __builtin_amdgcn_s_barrier();
    __builtin_amdgcn_sched_barrier(0);

    short8 bfrag[4];

    for (int i = 0; i < 8; ++i) {
        const int Tb = i * 4;
        const bool last = (i == 7);
#pragma unroll
        for (int ph = 0; ph < 8; ++ph) {
            const int tp = ph >> 1;
            const int h  = ph & 1;
            const int rg = tp;
            if (h == 0) {
#pragma unroll
                for (int ni = 0; ni < 4; ++ni)
                    bfrag[ni] = *(const short8*)((char*)&Bs[rg][0] +
                                (wn * 64 + ni * 16 + fr) * 64 + ksz);
            }
            short8 afrag[4];
#pragma unroll
            for (int mi = 0; mi < 4; ++mi)
                afrag[mi] = *(const short8*)((char*)&As[rg][0] +
                            (wm * 128 + h * 64 + mi * 16 + fr) * 64 + ksz);
            {
                const int SX = Tb + 3 + tp;
                if (SX < 32) {
                    if (h == 0) STAGE_A(SX); else STAGE_B(SX);
                }
            }
            if (ph == 3) {
                if (last) asm volatile("s_waitcnt vmcnt(0)" ::: "memory");
                else      asm volatile("s_waitcnt vmcnt(4)" ::: "memory");
            } else if (ph == 7) {
                if (!last) asm volatile("s_waitcnt vmcnt(4)" ::: "memory");
            }
            __builtin_amdgcn_s_barrier();
            asm volatile("s_waitcnt lgkmcnt(0)" ::: "memory");
            __builtin_amdgcn_sched_barrier(0);
            __builtin_amdgcn_s_setprio(1);
#pragma unroll
            for (int mi = 0; mi < 4; ++mi)
#pragma unroll
                for (int ni = 0; ni < 4; ++ni)
                    acc[h * 4 + mi][ni] = __builtin_amdgcn_mfma_f32_16x16x32_bf16(
                        afrag[mi], bfrag[ni], acc[h * 4 + mi][ni], 0, 0, 0);
            __builtin_amdgcn_s_setprio(0);
            __builtin_amdgcn_sched_barrier(0);
            __builtin_amdgcn_s_barrier();
            __builtin_amdgcn_sched_barrier(0);
        }
    }
#undef STAGE_A
#undef STAGE_B

    const int c = lane & 15, rg2 = lane >> 4;
#pragma unroll
    for (int mi = 0; mi < 8; ++mi)
#pragma unroll
        for (int ni = 0; ni < 4; ++ni)
#pragma unroll
            for (int j = 0; j < 4; ++j) {
                const long row = row0 + wm * 128 + mi * 16 + rg2 * 4 + j;
                const int  col = col0 + wn * 64 + ni * 16 + c;
                C[row * D_DIM + col] = resid[row * D_DIM + col] + acc[mi][ni][j];
            }
}

// ---------------------------------------------------------------------------
extern "C" void kernel_launch(void* const* d_in, const int* in_sizes, int n_in,
                              void* d_out, int out_size, void* d_ws, size_t ws_size,
                              hipStream_t stream)
{
    const float* x    = (const float*)d_in[0];
    const float* ctx  = (const float*)d_in[1];
    const int*   cidx = (const int*)d_in[2];
    const float* gq   = (const float*)d_in[3];
    const float* gkv  = (const float*)d_in[4];
    const float* Wq   = (const float*)d_in[5];
    const float* Wk   = (const float*)d_in[6];
    const float* Wv   = (const float*)d_in[7];
    const float* Wo   = (const float*)d_in[8];
    float* out = (float*)d_out;

    char* ws = (char*)d_ws;
    const size_t MB = 1 << 20;
    unsigned short* wqT_hi = (unsigned short*)(ws + 0 * MB);
    unsigned short* wqT_lo = (unsigned short*)(ws + 2 * MB);
    unsigned short* wk_hi  = (unsigned short*)(ws + 4 * MB);
    unsigned short* wk_lo  = (unsigned short*)(ws + 6 * MB);
    unsigned short* wv_hi  = (unsigned short*)(ws + 8 * MB);
    unsigned short* wv_lo  = (unsigned short*)(ws + 10 * MB);
    unsigned short* wo_b   = (unsigned short*)(ws + 12 * MB);
    unsigned short* ch = (unsigned short*)(ws + 14 * MB);
    unsigned short* cl = (unsigned short*)(ws + 16 * MB);
    unsigned short* kh = (unsigned short*)(ws + 18 * MB);
    unsigned short* kl = (unsigned short*)(ws + 20 * MB);
    float* v_f = (float*)(ws + 22 * MB);                      // 4MB
    unsigned short* Uh = (unsigned short*)(ws + 26 * MB);     // 32MB (26..58)
    unsigned short* Ul = (unsigned short*)(ws + 58 * MB);     // 32MB (58..90)
    unsigned short* ao_b = (unsigned short*)(ws + 26 * MB);   // 32MB, ALIASES Uh
        // (Uh dead after score_gemm; attnout writes ao afterwards)
    float* sbuf  = (float*)(ws + 91 * MB);                    // 2 x 3MB (91..97)
    float* ssbuf = (float*)(ws + 97 * MB);                    // 2 x 64KB
    int2*  bounds = (int2*)(ws + 98 * MB);                    // 8KB; total ~98MB

    convw_kernel<<<3072, 256, 0, stream>>>(Wk, Wv, Wo, gkv,
                                           wk_hi, wk_lo, wv_hi, wv_lo, wo_b);
    transq_kernel<<<256, 256, 0, stream>>>(Wq, gq, wqT_hi, wqT_lo);
    rms_split_kernel<<<1024, 256, 0, stream>>>(ctx, ch, cl);
    bounds_kernel<<<4, 256, 0, stream>>>(cidx, bounds);
    gemm_kv<<<dim3(8, 8, 2), 256, 0, stream>>>(ch, cl, wk_hi, wk_lo, wv_hi,
                                               kh, kl, v_f);
    gemm_U<<<dim3(8, 8, 16), 256, 0, stream>>>(kh, kl, wqT_hi, wqT_lo, Uh, Ul);
    score_gemm<<<dim3(64, 2, 8), 256, 0, stream>>>(x, cidx, bounds, Uh, Ul,
                                                   sbuf, ssbuf);
    attnout_kernel<<<1024, 256, 0, stream>>>(sbuf, ssbuf, v_f, cidx, ao_b);
    gemm_out256<<<256, 512, 0, stream>>>(ao_b, wo_b, out, x);
}

// Round 19
// 190.464 us; speedup vs baseline: 1.1975x; 1.0233x over previous
//
#include <hip/hip_runtime.h>
#include <hip/hip_bf16.h>
#include <stdint.h>

// B=4, T=4096, K=256, D=1024, H=16, hd=64
#define D_DIM 1024

using f32x4  = __attribute__((ext_vector_type(4))) float;
using short8 = __attribute__((ext_vector_type(8))) short;

__device__ __forceinline__ float bf2f(unsigned short u) {
    union { unsigned int i; float f; } v; v.i = ((unsigned int)u) << 16; return v.f;
}
__device__ __forceinline__ unsigned short f2bf(float f) {
    union { float f; unsigned int i; } v; v.f = f;
    unsigned int x = v.i;
    return (unsigned short)((x + 0x7fffu + ((x >> 16) & 1u)) >> 16);  // RNE
}
__device__ __forceinline__ void gload16(const void* g, void* l) {
    __builtin_amdgcn_global_load_lds(
        (const __attribute__((address_space(1))) void*)g,
        (__attribute__((address_space(3))) void*)l, 16, 0, 0);
}

// ---------------------------------------------------------------------------
// prep: fused {convw (3072 blk) | transq (256 blk) | rms_split ctx (1024 blk)
// | bounds (4 blk)}. Each block takes exactly one branch -> __syncthreads
// inside a branch is block-uniform (safe). LDS = max branch (transq 16.6KB).
// ---------------------------------------------------------------------------
__global__ __launch_bounds__(256)
void prep_kernel(const float* __restrict__ Wk, const float* __restrict__ Wv,
                 const float* __restrict__ Wo, const float* __restrict__ Wq,
                 const float* __restrict__ gkv, const float* __restrict__ gq,
                 const float* __restrict__ ctx, const int* __restrict__ cidx,
                 unsigned short* __restrict__ wk_hi, unsigned short* __restrict__ wk_lo,
                 unsigned short* __restrict__ wv_hi, unsigned short* __restrict__ wv_lo,
                 unsigned short* __restrict__ wo_b,
                 unsigned short* __restrict__ wqT_hi, unsigned short* __restrict__ wqT_lo,
                 unsigned short* __restrict__ ch, unsigned short* __restrict__ cl,
                 int2* __restrict__ bounds)
{
    __shared__ float tile[64][65];   // transq branch; others use a sliver
    const int blk = blockIdx.x;
    const int tid = threadIdx.x;

    if (blk < 3072) {
        // ---- convw: Wk,Wv gamma-folded hi/lo; Wo bf16 ----
        const int e   = (blk * 256 + tid) * 4;
        const int sel = e >> 20;
        const int off = e & 0xFFFFF;
        const float* src = sel == 0 ? Wk : sel == 1 ? Wv : Wo;
        float4 v = *(const float4*)(src + off);
        if (sel < 2) {
            float4 g = *(const float4*)(gkv + (off & 1023));
            v.x *= g.x; v.y *= g.y; v.z *= g.z; v.w *= g.w;
            ushort4 h, l;
            h.x = f2bf(v.x); l.x = f2bf(v.x - bf2f(h.x));
            h.y = f2bf(v.y); l.y = f2bf(v.y - bf2f(h.y));
            h.z = f2bf(v.z); l.z = f2bf(v.z - bf2f(h.z));
            h.w = f2bf(v.w); l.w = f2bf(v.w - bf2f(h.w));
            unsigned short* hi = sel == 0 ? wk_hi : wv_hi;
            unsigned short* lo = sel == 0 ? wk_lo : wv_lo;
            *(ushort4*)(hi + off) = h;
            *(ushort4*)(lo + off) = l;
        } else {
            ushort4 o;
            o.x = f2bf(v.x); o.y = f2bf(v.y); o.z = f2bf(v.z); o.w = f2bf(v.w);
            *(ushort4*)(wo_b + off) = o;
        }
    } else if (blk < 3328) {
        // ---- transq: wqT[i][c] = gq[i] * Wq[c][i], split hi/lo ----
        const int bb = blk - 3072;
        const int c0 = (bb & 15) * 64;
        const int i0 = (bb >> 4) * 64;
#pragma unroll
        for (int j = 0; j < 4; ++j) {
            const int e  = tid + j * 256;
            const int rl = e >> 4;
            const int q4 = e & 15;
            float4 v = *(const float4*)(Wq + (long)(c0 + rl) * 1024 + i0 + q4 * 4);
            tile[q4 * 4 + 0][rl] = v.x;
            tile[q4 * 4 + 1][rl] = v.y;
            tile[q4 * 4 + 2][rl] = v.z;
            tile[q4 * 4 + 3][rl] = v.w;
        }
        __syncthreads();
#pragma unroll
        for (int j = 0; j < 4; ++j) {
            const int e  = tid + j * 256;
            const int il = e >> 4;
            const int s4 = e & 15;
            const float g = gq[i0 + il];
            float v0 = tile[il][s4 * 4 + 0] * g;
            float v1 = tile[il][s4 * 4 + 1] * g;
            float v2 = tile[il][s4 * 4 + 2] * g;
            float v3 = tile[il][s4 * 4 + 3] * g;
            ushort4 hh, ll;
            hh.x = f2bf(v0); ll.x = f2bf(v0 - bf2f(hh.x));
            hh.y = f2bf(v1); ll.y = f2bf(v1 - bf2f(hh.y));
            hh.z = f2bf(v2); ll.z = f2bf(v2 - bf2f(hh.z));
            hh.w = f2bf(v3); ll.w = f2bf(v3 - bf2f(hh.w));
            const long o = (long)(i0 + il) * 1024 + c0 + s4 * 4;
            *(ushort4*)(wqT_hi + o) = hh;
            *(ushort4*)(wqT_lo + o) = ll;
        }
    } else if (blk < 4352) {
        // ---- rms_split for ctx rows ----
        const long row = blk - 3328;
        float4 v = ((const float4*)(ctx + row * D_DIM))[tid];
        float ss = v.x*v.x + v.y*v.y + v.z*v.z + v.w*v.w;
#pragma unroll
        for (int m = 32; m; m >>= 1) ss += __shfl_xor(ss, m);
        float* red = &tile[0][0];
        if ((tid & 63) == 0) red[tid >> 6] = ss;
        __syncthreads();
        const float tot = red[0] + red[1] + red[2] + red[3];
        const float scale = rsqrtf(tot * (1.0f / 1024.0f) + 1.1920929e-07f);
        v.x *= scale; v.y *= scale; v.z *= scale; v.w *= scale;
        ushort4 h, l;
        h.x = f2bf(v.x); l.x = f2bf(v.x - bf2f(h.x));
        h.y = f2bf(v.y); l.y = f2bf(v.y - bf2f(h.y));
        h.z = f2bf(v.z); l.z = f2bf(v.z - bf2f(h.z));
        h.w = f2bf(v.w); l.w = f2bf(v.w - bf2f(h.w));
        *(ushort4*)(ch + row * D_DIM + tid * 4) = h;
        *(ushort4*)(cl + row * D_DIM + tid * 4) = l;
    } else {
        // ---- bounds: per (b,p) band token range ----
        const int b = blk - 4352;
        const int p = tid;
        const int* ci = cidx + (b << 12);
        int l = 0, r = 4096;
        while (l < r) { int m = (l + r) >> 1; if (ci[m] < p - 1) l = m + 1; else r = m; }
        const int lo = l;
        r = 4096;
        while (l < r) { int m = (l + r) >> 1; if (ci[m] <= p + 1) l = m + 1; else r = m; }
        bounds[(b << 8) + p] = make_int2(lo, l);
    }
}

// ---------------------------------------------------------------------------
// gemm_kv: z=0: k split-precision -> kh/kl bf16. z=1: v ~= ch@Wv'_hi^T -> f32.
// ---------------------------------------------------------------------------
__global__ __launch_bounds__(256)
void gemm_kv(const unsigned short* __restrict__ ch, const unsigned short* __restrict__ cl,
             const unsigned short* __restrict__ wkh, const unsigned short* __restrict__ wkl,
             const unsigned short* __restrict__ wvh,
             unsigned short* __restrict__ kh, unsigned short* __restrict__ kl,
             float* __restrict__ v_f)
{
    __shared__ unsigned short Ah[4096], Al[4096], Bh[4096], Bl[4096];
    const bool full = (blockIdx.z == 0);
    const unsigned short* Bhp = full ? wkh : wvh;
    const unsigned short* Blp = wkl;

    const int tid = threadIdx.x, lane = tid & 63, wave = tid >> 6;
    const int wm = wave >> 1, wn = wave & 1;
    const long Arow0 = (long)blockIdx.y * 128;
    const int  Brow0 = blockIdx.x * 128;
    const int fr = lane & 15, ks = lane >> 4;
    const int ksz = (ks ^ ((fr >> 1) & 3)) << 4;
    const int kq  = ((tid & 3) ^ ((tid >> 3) & 3)) * 8;
    const int srow = tid >> 2;

    const long a_off0 = (Arow0 + srow) * D_DIM + kq;
    const long a_off1 = (Arow0 + srow + 64) * D_DIM + kq;
    const long b_off0 = (long)(Brow0 + srow) * D_DIM + kq;
    const long b_off1 = (long)(Brow0 + srow + 64) * D_DIM + kq;

    f32x4 acc[4][4] = {};
    char* AhB = (char*)Ah; char* AlB = (char*)Al;
    char* BhB = (char*)Bh; char* BlB = (char*)Bl;

    for (int kt = 0; kt < 32; ++kt) {
        const int k0 = kt * 32;
        gload16(ch + a_off0 + k0, AhB + tid * 16);
        gload16(ch + a_off1 + k0, AhB + 4096 + tid * 16);
        gload16(Bhp + b_off0 + k0, BhB + tid * 16);
        gload16(Bhp + b_off1 + k0, BhB + 4096 + tid * 16);
        if (full) {
            gload16(cl + a_off0 + k0, AlB + tid * 16);
            gload16(cl + a_off1 + k0, AlB + 4096 + tid * 16);
            gload16(Blp + b_off0 + k0, BlB + tid * 16);
            gload16(Blp + b_off1 + k0, BlB + 4096 + tid * 16);
        }
        __syncthreads();

        short8 ah[4], al[4], bh[4], bl[4];
#pragma unroll
        for (int mi = 0; mi < 4; ++mi) {
            const int aoff = (wm * 64 + mi * 16 + fr) * 64 + ksz;
            ah[mi] = *(const short8*)(AhB + aoff);
            if (full) al[mi] = *(const short8*)(AlB + aoff);
        }
#pragma unroll
        for (int ni = 0; ni < 4; ++ni) {
            const int boff = (wn * 64 + ni * 16 + fr) * 64 + ksz;
            bh[ni] = *(const short8*)(BhB + boff);
            if (full) bl[ni] = *(const short8*)(BlB + boff);
        }
#pragma unroll
        for (int mi = 0; mi < 4; ++mi)
#pragma unroll
            for (int ni = 0; ni < 4; ++ni) {
                acc[mi][ni] = __builtin_amdgcn_mfma_f32_16x16x32_bf16(ah[mi], bh[ni], acc[mi][ni], 0, 0, 0);
                if (full) {
                    acc[mi][ni] = __builtin_amdgcn_mfma_f32_16x16x32_bf16(al[mi], bh[ni], acc[mi][ni], 0, 0, 0);
                    acc[mi][ni] = __builtin_amdgcn_mfma_f32_16x16x32_bf16(ah[mi], bl[ni], acc[mi][ni], 0, 0, 0);
                }
            }
        __syncthreads();
    }

    const int c = lane & 15, r0 = (lane >> 4) * 4;
#pragma unroll
    for (int mi = 0; mi < 4; ++mi)
#pragma unroll
        for (int ni = 0; ni < 4; ++ni)
#pragma unroll
            for (int j = 0; j < 4; ++j) {
                const long row = Arow0 + wm * 64 + mi * 16 + r0 + j;
                const int  col = Brow0 + wn * 64 + ni * 16 + c;
                const float val = acc[mi][ni][j];
                if (full) {
                    const unsigned short hh = f2bf(val);
                    kh[row * D_DIM + col] = hh;
                    kl[row * D_DIM + col] = f2bf(val - bf2f(hh));
                } else {
                    v_f[row * D_DIM + col] = val;
                }
            }
}

// ---------------------------------------------------------------------------
// gemm_U: U[b,p,h][i] = sum_d (kh+kl)[(b,p),h*64+d]*(wqT_h+l)[i,h*64+d],
// epilogue -> bf16 hi/lo (Uh/Ul).
// ---------------------------------------------------------------------------
__global__ __launch_bounds__(256)
void gemm_U(const unsigned short* __restrict__ kh, const unsigned short* __restrict__ kl,
            const unsigned short* __restrict__ th, const unsigned short* __restrict__ tl,
            unsigned short* __restrict__ Uh, unsigned short* __restrict__ Ul)
{
    __shared__ unsigned short Ah[4096], Al[4096], Bh[4096], Bl[4096];
    const int h = blockIdx.z;
    const int tid = threadIdx.x, lane = tid & 63, wave = tid >> 6;
    const int wm = wave >> 1, wn = wave & 1;
    const long Arow0 = (long)blockIdx.y * 128;
    const int  Brow0 = blockIdx.x * 128;
    const int fr = lane & 15, ks = lane >> 4;
    const int ksz = (ks ^ ((fr >> 1) & 3)) << 4;
    const int kq  = ((tid & 3) ^ ((tid >> 3) & 3)) * 8;
    const int srow = tid >> 2;
    const int kb = h * 64;

    const long a_off0 = (Arow0 + srow) * D_DIM + kb + kq;
    const long a_off1 = (Arow0 + srow + 64) * D_DIM + kb + kq;
    const long b_off0 = (long)(Brow0 + srow) * D_DIM + kb + kq;
    const long b_off1 = (long)(Brow0 + srow + 64) * D_DIM + kb + kq;

    f32x4 acc[4][4] = {};
    char* AhB = (char*)Ah; char* AlB = (char*)Al;
    char* BhB = (char*)Bh; char* BlB = (char*)Bl;

    for (int kt = 0; kt < 2; ++kt) {
        const int k0 = kt * 32;
        gload16(kh + a_off0 + k0, AhB + tid * 16);
        gload16(kh + a_off1 + k0, AhB + 4096 + tid * 16);
        gload16(kl + a_off0 + k0, AlB + tid * 16);
        gload16(kl + a_off1 + k0, AlB + 4096 + tid * 16);
        gload16(th + b_off0 + k0, BhB + tid * 16);
        gload16(th + b_off1 + k0, BhB + 4096 + tid * 16);
        gload16(tl + b_off0 + k0, BlB + tid * 16);
        gload16(tl + b_off1 + k0, BlB + 4096 + tid * 16);
        __syncthreads();

        short8 ah[4], al[4], bh[4], bl[4];
#pragma unroll
        for (int mi = 0; mi < 4; ++mi) {
            const int aoff = (wm * 64 + mi * 16 + fr) * 64 + ksz;
            ah[mi] = *(const short8*)(AhB + aoff);
            al[mi] = *(const short8*)(AlB + aoff);
        }
#pragma unroll
        for (int ni = 0; ni < 4; ++ni) {
            const int boff = (wn * 64 + ni * 16 + fr) * 64 + ksz;
            bh[ni] = *(const short8*)(BhB + boff);
            bl[ni] = *(const short8*)(BlB + boff);
        }
#pragma unroll
        for (int mi = 0; mi < 4; ++mi)
#pragma unroll
            for (int ni = 0; ni < 4; ++ni) {
                acc[mi][ni] = __builtin_amdgcn_mfma_f32_16x16x32_bf16(ah[mi], bh[ni], acc[mi][ni], 0, 0, 0);
                acc[mi][ni] = __builtin_amdgcn_mfma_f32_16x16x32_bf16(al[mi], bh[ni], acc[mi][ni], 0, 0, 0);
                acc[mi][ni] = __builtin_amdgcn_mfma_f32_16x16x32_bf16(ah[mi], bl[ni], acc[mi][ni], 0, 0, 0);
            }
        __syncthreads();
    }

    const int c = lane & 15, r0 = (lane >> 4) * 4;
#pragma unroll
    for (int mi = 0; mi < 4; ++mi)
#pragma unroll
        for (int ni = 0; ni < 4; ++ni)
#pragma unroll
            for (int j = 0; j < 4; ++j) {
                const long row = Arow0 + wm * 64 + mi * 16 + r0 + j;
                const int  col = Brow0 + wn * 64 + ni * 16 + c;
                const float val = acc[mi][ni][j];
                const long o = ((long)row * 16 + h) * 1024 + col;
                const unsigned short hh = f2bf(val);
                Uh[o] = hh;
                Ul[o] = f2bf(val - bf2f(hh));
            }
}

// ---------------------------------------------------------------------------
// score v7 (r18-validated): 2-way K-split + precomputed bounds.
// ---------------------------------------------------------------------------
__global__ __launch_bounds__(256)
void score_gemm(const float* __restrict__ x, const int* __restrict__ cidx,
                const int2* __restrict__ bounds,
                const unsigned short* __restrict__ Uh, const unsigned short* __restrict__ Ul,
                float* __restrict__ sbuf, float* __restrict__ ssbuf)
{
    const int pg = blockIdx.x;
    const int mh = blockIdx.y;
    const int bz = blockIdx.z;
    const int b  = bz & 3;
    const int ksp = bz >> 2;
    const int kbase = ksp << 9;
    const int p0 = pg * 4;
    const int lo = bounds[(b << 8) + p0].x;
    const int hi = bounds[(b << 8) + p0 + 3].y;
    if (lo + mh * 64 >= hi) return;
    const int* ci = cidx + (b << 12);

    float* const sb = sbuf + (long)ksp * 786432;
    float* const ssb = ssbuf + (ksp << 14);

    __shared__ unsigned short AhS[2][2048], AlS[2][2048];
    __shared__ unsigned short UhS[2][2048], UlS[2][2048];

    const int tid = threadIdx.x, lane = tid & 63, wave = tid >> 6;
    const int fr = lane & 15;
    const int ks = lane >> 4;
    const int ksz = (ks ^ ((fr >> 1) & 3)) << 4;

    const int arow = tid >> 2, aq = tid & 3;
    const int aslot = aq ^ ((arow >> 1) & 3);
    const unsigned short* const Uhb = Uh + ((long)((b << 8) + p0) * 16) * 1024 + kbase;
    const unsigned short* const Ulb = Ul + ((long)((b << 8) + p0) * 16) * 1024 + kbase;
    const float* const xb = x + ((long)b << 12) * 1024 + kbase;

    for (int t0 = lo + mh * 64; t0 < hi; t0 += 128) {
        const int tc0 = (t0 + arow < hi) ? (t0 + arow) : (hi - 1);
        const float* xr = xb + (long)tc0 * 1024 + aq * 8;
        float ss = 0.f;

        gload16(Uhb + (long)arow * 1024 + aslot * 8, (char*)&UhS[0][0] + tid * 16);
        gload16(Ulb + (long)arow * 1024 + aslot * 8, (char*)&UlS[0][0] + tid * 16);
        {
            const float4 v0 = *(const float4*)(xr);
            const float4 v1 = *(const float4*)(xr + 4);
            ss += v0.x*v0.x + v0.y*v0.y + v0.z*v0.z + v0.w*v0.w
                + v1.x*v1.x + v1.y*v1.y + v1.z*v1.z + v1.w*v1.w;
            short8 hv, lv;
            unsigned short h_;
            h_ = f2bf(v0.x); hv[0] = (short)h_; lv[0] = (short)f2bf(v0.x - bf2f(h_));
            h_ = f2bf(v0.y); hv[1] = (short)h_; lv[1] = (short)f2bf(v0.y - bf2f(h_));
            h_ = f2bf(v0.z); hv[2] = (short)h_; lv[2] = (short)f2bf(v0.z - bf2f(h_));
            h_ = f2bf(v0.w); hv[3] = (short)h_; lv[3] = (short)f2bf(v0.w - bf2f(h_));
            h_ = f2bf(v1.x); hv[4] = (short)h_; lv[4] = (short)f2bf(v1.x - bf2f(h_));
            h_ = f2bf(v1.y); hv[5] = (short)h_; lv[5] = (short)f2bf(v1.y - bf2f(h_));
            h_ = f2bf(v1.z); hv[6] = (short)h_; lv[6] = (short)f2bf(v1.z - bf2f(h_));
            h_ = f2bf(v1.w); hv[7] = (short)h_; lv[7] = (short)f2bf(v1.w - bf2f(h_));
            *(short8*)((char*)&AhS[0][0] + arow * 64 + aslot * 16) = hv;
            *(short8*)((char*)&AlS[0][0] + arow * 64 + aslot * 16) = lv;
        }
        __syncthreads();

        f32x4 acc[4] = {};
        for (int t = 0; t < 16; ++t) {
            const int cur = t & 1, nxt = cur ^ 1;
            float4 v0, v1;
            if (t < 15) {
                const int k0n = (t + 1) * 32;
                gload16(Uhb + (long)arow * 1024 + k0n + aslot * 8, (char*)&UhS[nxt][0] + tid * 16);
                gload16(Ulb + (long)arow * 1024 + k0n + aslot * 8, (char*)&UlS[nxt][0] + tid * 16);
                v0 = *(const float4*)(xr + k0n);
                v1 = *(const float4*)(xr + k0n + 4);
            }

            const int aoff = cur * 4096 + (wave * 16 + fr) * 64 + ksz;
            const short8 ah = *(const short8*)((char*)&AhS[0][0] + aoff);
            const short8 al = *(const short8*)((char*)&AlS[0][0] + aoff);
#pragma unroll
            for (int ni = 0; ni < 4; ++ni) {
                const int boff = cur * 4096 + (ni * 16 + fr) * 64 + ksz;
                const short8 uh = *(const short8*)((char*)&UhS[0][0] + boff);
                const short8 ul = *(const short8*)((char*)&UlS[0][0] + boff);
                acc[ni] = __builtin_amdgcn_mfma_f32_16x16x32_bf16(ah, uh, acc[ni], 0, 0, 0);
                acc[ni] = __builtin_amdgcn_mfma_f32_16x16x32_bf16(al, uh, acc[ni], 0, 0, 0);
                acc[ni] = __builtin_amdgcn_mfma_f32_16x16x32_bf16(ah, ul, acc[ni], 0, 0, 0);
            }

            if (t < 15) {
                ss += v0.x*v0.x + v0.y*v0.y + v0.z*v0.z + v0.w*v0.w
                    + v1.x*v1.x + v1.y*v1.y + v1.z*v1.z + v1.w*v1.w;
                short8 hv, lv;
                unsigned short h_;
                h_ = f2bf(v0.x); hv[0] = (short)h_; lv[0] = (short)f2bf(v0.x - bf2f(h_));
                h_ = f2bf(v0.y); hv[1] = (short)h_; lv[1] = (short)f2bf(v0.y - bf2f(h_));
                h_ = f2bf(v0.z); hv[2] = (short)h_; lv[2] = (short)f2bf(v0.z - bf2f(h_));
                h_ = f2bf(v0.w); hv[3] = (short)h_; lv[3] = (short)f2bf(v0.w - bf2f(h_));
                h_ = f2bf(v1.x); hv[4] = (short)h_; lv[4] = (short)f2bf(v1.x - bf2f(h_));
                h_ = f2bf(v1.y); hv[5] = (short)h_; lv[5] = (short)f2bf(v1.y - bf2f(h_));
                h_ = f2bf(v1.z); hv[6] = (short)h_; lv[6] = (short)f2bf(v1.z - bf2f(h_));
                h_ = f2bf(v1.w); hv[7] = (short)h_; lv[7] = (short)f2bf(v1.w - bf2f(h_));
                *(short8*)((char*)&AhS[0][0] + nxt * 4096 + arow * 64 + aslot * 16) = hv;
                *(short8*)((char*)&AlS[0][0] + nxt * 4096 + arow * 64 + aslot * 16) = lv;
            }
            __syncthreads();
        }

        ss += __shfl_xor(ss, 1);
        ss += __shfl_xor(ss, 2);
        if (aq == 0 && t0 + arow < hi)
            ssb[(b << 12) + t0 + arow] = ss;

        const int hcol = lane & 15;
        const int r0j = (lane >> 4) * 4;
#pragma unroll
        for (int j = 0; j < 4; ++j) {
            const int trow = t0 + wave * 16 + r0j + j;
            if (trow < hi) {
                const long tg = ((long)b << 12) + trow;
                const int idx = ci[trow];
#pragma unroll
                for (int ni = 0; ni < 4; ++ni) {
                    const int dp = p0 + ni - idx + 1;
                    if (dp >= 0 && dp <= 2)
                        sb[(tg * 16 + hcol) * 3 + dp] = acc[ni][j];
                }
            }
        }
        __syncthreads();
    }
}

// ---------------------------------------------------------------------------
// attnout: dot = sum of K-halves; s = dot*rsqrt(mean xx+eps)/8; w=relu(s)^2,
// normalize, out = sum w*v. ao bf16.
// ---------------------------------------------------------------------------
__global__ __launch_bounds__(256)
void attnout_kernel(const float* __restrict__ sbuf, const float* __restrict__ ssbuf,
                    const float* __restrict__ vf, const int* __restrict__ cidx,
                    unsigned short* __restrict__ ao)
{
    const int tid = threadIdx.x;
    const int tg = tid >> 4, h = tid & 15;
    const int t = blockIdx.x * 16 + tg;
    const int b = t >> 12;
    const int idx = cidx[t];
    const float* sb0 = sbuf + ((long)t * 16 + h) * 3;
    const float* sb1 = sb0 + 786432;
    const float ssum = ssbuf[t] + ssbuf[t + 16384];
    const float scale = rsqrtf(ssum * (1.0f / 1024.0f) + 1.1920929e-07f) * 0.125f;
    float w0 = 0.f, w1 = 0.f, w2 = 0.f, wsum = 0.f;
    if (idx - 1 >= 0) { float s = (sb0[0] + sb1[0]) * scale; if (s > 0.f) { w0 = s * s; wsum += w0; } }
    { float s = (sb0[1] + sb1[1]) * scale; if (s > 0.f) { w1 = s * s; wsum += w1; } }
    if (idx + 1 < 256) { float s = (sb0[2] + sb1[2]) * scale; if (s > 0.f) { w2 = s * s; wsum += w2; } }
    const float inv = 1.0f / fmaxf(wsum, 1e-6f);
    w0 *= inv; w1 *= inv; w2 *= inv;
    const int p0 = idx > 0 ? idx - 1 : 0;
    const int p2 = idx < 255 ? idx + 1 : 255;
    const float4* v0 = (const float4*)(vf + ((long)(b * 256 + p0)) * 1024 + h * 64);
    const float4* v1 = (const float4*)(vf + ((long)(b * 256 + idx)) * 1024 + h * 64);
    const float4* v2 = (const float4*)(vf + ((long)(b * 256 + p2)) * 1024 + h * 64);
    ushort4* aop = (ushort4*)(ao + (long)t * 1024 + h * 64);
#pragma unroll
    for (int q = 0; q < 16; ++q) {
        float4 a0 = v0[q], a1 = v1[q], a2 = v2[q];
        ushort4 o;
        o.x = f2bf(w0 * a0.x + w1 * a1.x + w2 * a2.x);
        o.y = f2bf(w0 * a0.y + w1 * a1.y + w2 * a2.y);
        o.z = f2bf(w0 * a0.z + w1 * a1.z + w2 * a2.z);
        o.w = f2bf(w0 * a0.w + w1 * a1.w + w2 * a2.w);
        aop[q] = o;
    }
}

// ---------------------------------------------------------------------------
// out = x + ao @ Wo^T, 256x256, swizzled, 8-PHASE deep-pipelined (r15, win).
// ---------------------------------------------------------------------------
__global__ __launch_bounds__(512, 2)
void gemm_out256(const unsigned short* __restrict__ A,
                 const unsigned short* __restrict__ W,
                 float* __restrict__ C, const float* __restrict__ resid)
{
    __shared__ unsigned short As[4][8192];
    __shared__ unsigned short Bs[4][8192];

    const int lin = blockIdx.x;
    const int bx = (lin >> 3) & 3;
    const int by = ((lin >> 5) << 3) | (lin & 7);
    const long row0 = (long)by * 256;
    const int  col0 = bx * 256;

    const int tid = threadIdx.x, lane = tid & 63, wave = tid >> 6;
    const int wm = wave >> 2, wn = wave & 3;
    const int fr = lane & 15, ks = lane >> 4;
    const int ksz = (ks ^ ((fr >> 1) & 3)) << 4;
    const int kq  = ((tid & 3) ^ ((tid >> 3) & 3)) * 8;
    const int srow = tid >> 2;

    const long a_off0 = (row0 + srow) * D_DIM + kq;
    const long a_off1 = (row0 + 128 + srow) * D_DIM + kq;
    const long b_off0 = (long)(col0 + srow) * D_DIM + kq;
    const long b_off1 = (long)(col0 + 128 + srow) * D_DIM + kq;

    f32x4 acc[8][4] = {};

#define STAGE_A(X) do { const int kofs_ = (X) * 32;                          \
    char* base_ = (char*)&As[(X) & 3][0];                                    \
    gload16(A + a_off0 + kofs_, base_ + tid * 16);                           \
    gload16(A + a_off1 + kofs_, base_ + 8192 + tid * 16); } while (0)
#define STAGE_B(X) do { const int kofs_ = (X) * 32;                          \
    char* base_ = (char*)&Bs[(X) & 3][0];                                    \
    gload16(W + b_off0 + kofs_, base_ + tid * 16);                           \
    gload16(W + b_off1 + kofs_, base_ + 8192 + tid * 16); } while (0)

    STAGE_A(0); STAGE_B(0); STAGE_A(1); STAGE_B(1); STAGE_A(2); STAGE_B(2);
    asm volatile("s_waitcnt vmcnt(4)" ::: "memory");
    __builtin_amdgcn_s_barrier();
    __builtin_amdgcn_sched_barrier(0);

    short8 bfrag[4];

    for (int i = 0; i < 8; ++i) {
        const int Tb = i * 4;
        const bool last = (i == 7);
#pragma unroll
        for (int ph = 0; ph < 8; ++ph) {
            const int tp = ph >> 1;
            const int h  = ph & 1;
            const int rg = tp;
            if (h == 0) {
#pragma unroll
                for (int ni = 0; ni < 4; ++ni)
                    bfrag[ni] = *(const short8*)((char*)&Bs[rg][0] +
                                (wn * 64 + ni * 16 + fr) * 64 + ksz);
            }
            short8 afrag[4];
#pragma unroll
            for (int mi = 0; mi < 4; ++mi)
                afrag[mi] = *(const short8*)((char*)&As[rg][0] +
                            (wm * 128 + h * 64 + mi * 16 + fr) * 64 + ksz);
            {
                const int SX = Tb + 3 + tp;
                if (SX < 32) {
                    if (h == 0) STAGE_A(SX); else STAGE_B(SX);
                }
            }
            if (ph == 3) {
                if (last) asm volatile("s_waitcnt vmcnt(0)" ::: "memory");
                else      asm volatile("s_waitcnt vmcnt(4)" ::: "memory");
            } else if (ph == 7) {
                if (!last) asm volatile("s_waitcnt vmcnt(4)" ::: "memory");
            }
            __builtin_amdgcn_s_barrier();
            asm volatile("s_waitcnt lgkmcnt(0)" ::: "memory");
            __builtin_amdgcn_sched_barrier(0);
            __builtin_amdgcn_s_setprio(1);
#pragma unroll
            for (int mi = 0; mi < 4; ++mi)
#pragma unroll
                for (int ni = 0; ni < 4; ++ni)
                    acc[h * 4 + mi][ni] = __builtin_amdgcn_mfma_f32_16x16x32_bf16(
                        afrag[mi], bfrag[ni], acc[h * 4 + mi][ni], 0, 0, 0);
            __builtin_amdgcn_s_setprio(0);
            __builtin_amdgcn_sched_barrier(0);
            __builtin_amdgcn_s_barrier();
            __builtin_amdgcn_sched_barrier(0);
        }
    }
#undef STAGE_A
#undef STAGE_B

    const int c = lane & 15, rg2 = lane >> 4;
#pragma unroll
    for (int mi = 0; mi < 8; ++mi)
#pragma unroll
        for (int ni = 0; ni < 4; ++ni)
#pragma unroll
            for (int j = 0; j < 4; ++j) {
                const long row = row0 + wm * 128 + mi * 16 + rg2 * 4 + j;
                const int  col = col0 + wn * 64 + ni * 16 + c;
                C[row * D_DIM + col] = resid[row * D_DIM + col] + acc[mi][ni][j];
            }
}

// ---------------------------------------------------------------------------
extern "C" void kernel_launch(void* const* d_in, const int* in_sizes, int n_in,
                              void* d_out, int out_size, void* d_ws, size_t ws_size,
                              hipStream_t stream)
{
    const float* x    = (const float*)d_in[0];
    const float* ctx  = (const float*)d_in[1];
    const int*   cidx = (const int*)d_in[2];
    const float* gq   = (const float*)d_in[3];
    const float* gkv  = (const float*)d_in[4];
    const float* Wq   = (const float*)d_in[5];
    const float* Wk   = (const float*)d_in[6];
    const float* Wv   = (const float*)d_in[7];
    const float* Wo   = (const float*)d_in[8];
    float* out = (float*)d_out;

    char* ws = (char*)d_ws;
    const size_t MB = 1 << 20;
    unsigned short* wqT_hi = (unsigned short*)(ws + 0 * MB);
    unsigned short* wqT_lo = (unsigned short*)(ws + 2 * MB);
    unsigned short* wk_hi  = (unsigned short*)(ws + 4 * MB);
    unsigned short* wk_lo  = (unsigned short*)(ws + 6 * MB);
    unsigned short* wv_hi  = (unsigned short*)(ws + 8 * MB);
    unsigned short* wv_lo  = (unsigned short*)(ws + 10 * MB);
    unsigned short* wo_b   = (unsigned short*)(ws + 12 * MB);
    unsigned short* ch = (unsigned short*)(ws + 14 * MB);
    unsigned short* cl = (unsigned short*)(ws + 16 * MB);
    unsigned short* kh = (unsigned short*)(ws + 18 * MB);
    unsigned short* kl = (unsigned short*)(ws + 20 * MB);
    float* v_f = (float*)(ws + 22 * MB);                      // 4MB
    unsigned short* Uh = (unsigned short*)(ws + 26 * MB);     // 32MB (26..58)
    unsigned short* Ul = (unsigned short*)(ws + 58 * MB);     // 32MB (58..90)
    unsigned short* ao_b = (unsigned short*)(ws + 26 * MB);   // 32MB, ALIASES Uh
        // (Uh dead after score_gemm; attnout writes ao afterwards)
    float* sbuf  = (float*)(ws + 91 * MB);                    // 2 x 3MB (91..97)
    float* ssbuf = (float*)(ws + 97 * MB);                    // 2 x 64KB
    int2*  bounds = (int2*)(ws + 98 * MB);                    // 8KB; total ~98MB

    // 1. fused preprocessing: convw | transq | rms_split(ctx) | bounds
    prep_kernel<<<4356, 256, 0, stream>>>(Wk, Wv, Wo, Wq, gkv, gq, ctx, cidx,
                                          wk_hi, wk_lo, wv_hi, wv_lo, wo_b,
                                          wqT_hi, wqT_lo, ch, cl, bounds);
    // 2. k (split bf16), v (f32)
    gemm_kv<<<dim3(8, 8, 2), 256, 0, stream>>>(ch, cl, wk_hi, wk_lo, wv_hi,
                                               kh, kl, v_f);
    // 3. U = per-head Wq'^T k, bf16 hi/lo
    gemm_U<<<dim3(8, 8, 16), 256, 0, stream>>>(kh, kl, wqT_hi, wqT_lo, Uh, Ul);
    // 4. band scores (2-way K-split, precomputed bounds)
    score_gemm<<<dim3(64, 2, 8), 256, 0, stream>>>(x, cidx, bounds, Uh, Ul,
                                                   sbuf, ssbuf);
    // 5. normalize + weighted V -> ao
    attnout_kernel<<<1024, 256, 0, stream>>>(sbuf, ssbuf, v_f, cidx, ao_b);
    // 6. out = x + ao @ Wo^T (8-phase)
    gemm_out256<<<256, 512, 0, stream>>>(ao_b, wo_b, out, x);
}